// Round 6
// baseline (376.832 us; speedup 1.0000x reference)
//
#include <hip/hip_runtime.h>

#define BB 2
#define CC 16
#define BC 32
#define FF 256
#define WW 512
#define HH 8
#define DH 32

using bf16x8 = __attribute__((ext_vector_type(8))) __bf16;
using f32x4  = __attribute__((ext_vector_type(4))) float;
using us8    = __attribute__((ext_vector_type(8))) unsigned short;
using us4    = __attribute__((ext_vector_type(4))) unsigned short;

__device__ __forceinline__ float bf2f(unsigned short u) {
    union { unsigned int i; float f; } x; x.i = ((unsigned int)u) << 16; return x.f;
}
__device__ __forceinline__ unsigned short f2bf(float f) {
    union { float f; unsigned int i; } x; x.f = f;
    unsigned int r = x.i + 0x7fffu + ((x.i >> 16) & 1u);   // round-nearest-even
    return (unsigned short)(r >> 16);
}
__device__ __forceinline__ f32x4 mfma16(bf16x8 a, bf16x8 b, f32x4 c) {
    return __builtin_amdgcn_mfma_f32_16x16x32_bf16(a, b, c, 0, 0, 0);
}

// ---------------- f32 -> bf16 bulk convert (weights) ----------------
__global__ __launch_bounds__(256) void cvt_bf16(
    const float* __restrict__ src, unsigned short* __restrict__ dst, int n8) {
    int i = blockIdx.x * 256 + threadIdx.x;
    if (i >= n8) return;
    const float4* s = (const float4*)src + (size_t)i * 2;
    float4 a = s[0], b = s[1];
    us8 p;
    p[0] = f2bf(a.x); p[1] = f2bf(a.y); p[2] = f2bf(a.z); p[3] = f2bf(a.w);
    p[4] = f2bf(b.x); p[5] = f2bf(b.y); p[6] = f2bf(b.z); p[7] = f2bf(b.w);
    *((us8*)dst + i) = p;
}

// ---------------- LayerNorm over f -> [f][w] bf16 ----------------
__global__ __launch_bounds__(256) void ln_kernel(
    const float* __restrict__ x, const float* __restrict__ g,
    const float* __restrict__ bta, unsigned short* __restrict__ out) {
    int bc = blockIdx.x;
    int c = bc & (CC - 1);
    int w = blockIdx.y * 256 + threadIdx.x;
    const float* xp = x + ((size_t)bc * FF) * WW + w;
    float s = 0.f, s2 = 0.f;
#pragma unroll 4
    for (int f = 0; f < FF; ++f) { float t = xp[(size_t)f * WW]; s += t; s2 += t * t; }
    float m = s * (1.f / FF);
    float v = s2 * (1.f / FF) - m * m;
    float r = rsqrtf(v + 1e-5f);
    unsigned short* op = out + ((size_t)bc * FF) * WW + w;
    const float* gp = g + c * FF;
    const float* bp = bta + c * FF;
#pragma unroll 4
    for (int f = 0; f < FF; ++f) {
        float t = (xp[(size_t)f * WW] - m) * r * gp[f] + bp[f];
        op[(size_t)f * WW] = f2bf(t);
    }
}

// ---------------- LayerNorm over f -> TRANSPOSED [w][f] bf16 ----------------
__global__ __launch_bounds__(256) void ln_t_kernel(
    const float* __restrict__ x, const float* __restrict__ g,
    const float* __restrict__ bta, unsigned short* __restrict__ out) {
    int bc = blockIdx.x;
    int c = bc & (CC - 1);
    int w = blockIdx.y * 256 + threadIdx.x;
    const float* xp = x + ((size_t)bc * FF) * WW + w;
    float s = 0.f, s2 = 0.f;
#pragma unroll 4
    for (int f = 0; f < FF; ++f) { float t = xp[(size_t)f * WW]; s += t; s2 += t * t; }
    float m = s * (1.f / FF);
    float v = s2 * (1.f / FF) - m * m;
    float r = rsqrtf(v + 1e-5f);
    unsigned short* op = out + ((size_t)bc * WW + w) * FF;
    const float* gp = g + c * FF;
    const float* bp = bta + c * FF;
    for (int f8 = 0; f8 < FF / 8; ++f8) {
        us8 pk;
#pragma unroll
        for (int e = 0; e < 8; ++e) {
            int f = f8 * 8 + e;
            float t = (xp[(size_t)f * WW] - m) * r * gp[f] + bp[f];
            pk[e] = f2bf(t);
        }
        *(us8*)(op + f8 * 8) = pk;
    }
}

// ---------------- conv weight repack ----------------
__global__ __launch_bounds__(256) void wrepack(
    const float* __restrict__ wq, const float* __restrict__ wk, const float* __restrict__ wv,
    unsigned short* __restrict__ Aw) {
    int idx = blockIdx.x * 256 + threadIdx.x;   // < 3*2560
    int tensor = idx / 2560;
    int r = idx - tensor * 2560;
    int tp = r >> 9, co = (r >> 5) & 15, k = r & 31;
    int tap = tp * 2 + (k >> 4), ci = k & 15;
    float v = 0.f;
    if (tap < 9) {
        const float* w = tensor == 0 ? wq : (tensor == 1 ? wk : wv);
        v = w[(co * 16 + ci) * 9 + tap];
    }
    Aw[idx] = f2bf(v);
}

// ---------------- MFMA conv3x3 ----------------
__global__ __launch_bounds__(256) void conv3_mfma(
    const unsigned short* __restrict__ n1, const unsigned short* __restrict__ Aw,
    unsigned short* __restrict__ oq, unsigned short* __restrict__ ok,
    unsigned short* __restrict__ ov) {
    __shared__ __align__(16) unsigned short Xl[6][68][16];
    const int b = blockIdx.z;
    const int f0 = blockIdx.y * 4;
    const int w0 = blockIdx.x * 64;
    const int tx = threadIdx.x;
    const int lane = tx & 63, wid = tx >> 6;
    const int lr = lane & 15, lg = lane >> 4;
    {
        uint4 z{0, 0, 0, 0};
        for (int i = tx; i < 816; i += 256) ((uint4*)Xl)[i] = z;
    }
    __syncthreads();
    for (int task = tx; task < 960; task += 256) {
        int c = task % 10;
        int fr = (task / 10) % 6;
        int ci = task / 60;
        int fy = f0 - 1 + fr;
        int wx = w0 - 8 + c * 8;
        if (fy >= 0 && fy < FF && wx >= 0 && wx <= WW - 8) {
            us8 v = *(const us8*)(n1 + ((size_t)(b * CC + ci) * FF + fy) * WW + wx);
#pragma unroll
            for (int e = 0; e < 8; ++e) {
                int wl = c * 8 + e - 7;
                if (wl >= 0 && wl < 66) Xl[fr][wl][ci] = v[e];
            }
        }
    }
    __syncthreads();
    bf16x8 A[3][5];
#pragma unroll
    for (int t3 = 0; t3 < 3; ++t3)
#pragma unroll
        for (int t = 0; t < 5; ++t)
            A[t3][t] = *(const bf16x8*)(Aw + ((t3 * 5 + t) * 16 + lr) * 32 + lg * 8);
    const bool h = (lane & 32) != 0;
    int doff[5];
    doff[0] = (h ? (-68 * 32) : ((-68 - 1) * 32));
    doff[1] = (h ? (-1 * 32) : ((-68 + 1) * 32));
    doff[2] = (h ? (1 * 32) : 0);
    doff[3] = (h ? (68 * 32) : ((68 - 1) * 32));
    doff[4] = ((68 + 1) * 32);
    const int fl = wid + 1;
    const int fglob = f0 + wid;
    char* xbase = (char*)Xl + (fl * 68 + 1) * 32 + ((lg & 1) ? 16 : 0);
#pragma unroll
    for (int pt = 0; pt < 4; ++pt) {
        char* bb = xbase + (pt * 16 + lr) * 32;
        bf16x8 Bf[5];
#pragma unroll
        for (int t = 0; t < 5; ++t) Bf[t] = *(const bf16x8*)(bb + doff[t]);
        f32x4 aq = {0.f, 0.f, 0.f, 0.f}, ak = {0.f, 0.f, 0.f, 0.f}, av = {0.f, 0.f, 0.f, 0.f};
#pragma unroll
        for (int t = 0; t < 5; ++t) {
            aq = mfma16(A[0][t], Bf[t], aq);
            ak = mfma16(A[1][t], Bf[t], ak);
            av = mfma16(A[2][t], Bf[t], av);
        }
        int w = w0 + pt * 16 + lr;
#pragma unroll
        for (int r = 0; r < 4; ++r) {
            int co = lg * 4 + r;
            size_t o = ((size_t)(b * CC + co) * FF + fglob) * WW + w;
            oq[o] = f2bf(aq[r]);
            ok[o] = f2bf(ak[r]);
            ov[o] = f2bf(av[r]);
        }
    }
}

// ---------------- 128x128-tile MFMA GEMM: y[bc,g,w] = sum_f W[c,g,f] T[bc,f,w] ----------------
// A = bf16 weights [c][M][K] (k-contig). BSRC 0: Tt[bc][w][f]; BSRC 1: T[bc][f][w].
// MODE 0: bf16 [g][w]; MODE 1: f32 += [g][w]; MODE 2: bf16 [w][g].
// LDS swizzle: A slot = seg ^ (row&7); B slot = seg ^ (row&7) ^ ((row>>3)&7).
template <int K, int M, int BSRC, int MODE>
__global__ __launch_bounds__(256, 2) void mgemm2(
    const unsigned short* __restrict__ Wb, const unsigned short* __restrict__ T,
    unsigned short* __restrict__ ob, float* __restrict__ of) {
    __shared__ __align__(16) unsigned short Al[128 * 64];
    __shared__ __align__(16) unsigned short Bl[128 * 64];
    const int bc = blockIdx.x, c = bc & 15;
    const int G0 = blockIdx.y * 128, W0 = blockIdx.z * 128;
    const int tx = threadIdx.x;
    const int lane = tx & 63, wid = tx >> 6;
    const int lr = lane & 15, lg = lane >> 4;
    const int wr = wid >> 1, wc = wid & 1;
    const unsigned short* Ab = Wb + ((size_t)c * M + G0) * K;
    f32x4 acc[4][4];
#pragma unroll
    for (int i = 0; i < 4; ++i)
#pragma unroll
        for (int j = 0; j < 4; ++j) acc[i][j] = (f32x4){0.f, 0.f, 0.f, 0.f};

    for (int f0 = 0; f0 < K; f0 += 64) {
        // stage A (128 g x 64 k)
#pragma unroll
        for (int rep = 0; rep < 4; ++rep) {
            int idx = tx + rep * 256;
            int row = idx >> 3, seg = idx & 7;
            us8 v = *(const us8*)(Ab + (size_t)row * K + f0 + seg * 8);
            *(us8*)((char*)Al + row * 128 + ((seg ^ (row & 7)) << 4)) = v;
        }
        // stage B (128 w x 64 k)
        if (BSRC == 0) {
            const unsigned short* Tb = T + ((size_t)bc * WW + W0) * K;
#pragma unroll
            for (int rep = 0; rep < 4; ++rep) {
                int idx = tx + rep * 256;
                int row = idx >> 3, seg = idx & 7;
                us8 v = *(const us8*)(Tb + (size_t)row * K + f0 + seg * 8);
                *(us8*)((char*)Bl + row * 128 +
                        ((seg ^ (row & 7) ^ ((row >> 3) & 7)) << 4)) = v;
            }
        } else {
            const unsigned short* Tb = T + (size_t)bc * K * WW;
            const int wseg = tx & 15, fgrp = tx >> 4;
            us8 tv[4];
#pragma unroll
            for (int i = 0; i < 4; ++i)
                tv[i] = *(const us8*)(Tb + (size_t)(f0 + fgrp * 4 + i) * WW + W0 + wseg * 8);
#pragma unroll
            for (int j = 0; j < 8; ++j) {
                int w = wseg * 8 + j;
                us4 p; p.x = tv[0][j]; p.y = tv[1][j]; p.z = tv[2][j]; p.w = tv[3][j];
                *(us4*)((char*)Bl + w * 128 +
                        ((((fgrp >> 1) ^ (w & 7) ^ ((w >> 3) & 7)) << 4)) + (fgrp & 1) * 8) = p;
            }
        }
        __syncthreads();
#pragma unroll
        for (int kc = 0; kc < 2; ++kc) {
            bf16x8 af[4], bf[4];
#pragma unroll
            for (int i = 0; i < 4; ++i) {
                int gr = wr * 64 + i * 16 + lr;
                af[i] = *(const bf16x8*)((char*)Al + gr * 128 +
                        (((kc * 4 + lg) ^ (gr & 7)) << 4));
                int wrw = wc * 64 + i * 16 + lr;
                bf[i] = *(const bf16x8*)((char*)Bl + wrw * 128 +
                        (((kc * 4 + lg) ^ (wrw & 7) ^ ((wrw >> 3) & 7)) << 4));
            }
#pragma unroll
            for (int i = 0; i < 4; ++i)
#pragma unroll
                for (int j = 0; j < 4; ++j)
                    acc[i][j] = mfma16(af[i], bf[j], acc[i][j]);
        }
        __syncthreads();
    }
#pragma unroll
    for (int i = 0; i < 4; ++i)
#pragma unroll
        for (int j = 0; j < 4; ++j) {
            int g = G0 + wr * 64 + i * 16 + lg * 4;
            int w = W0 + wc * 64 + j * 16 + lr;
            if (MODE == 2) {
                us4 pk;
                pk.x = f2bf(acc[i][j][0]); pk.y = f2bf(acc[i][j][1]);
                pk.z = f2bf(acc[i][j][2]); pk.w = f2bf(acc[i][j][3]);
                *(us4*)(ob + ((size_t)bc * WW + w) * M + g) = pk;
            } else {
#pragma unroll
                for (int r = 0; r < 4; ++r) {
                    size_t o = ((size_t)bc * M + g + r) * WW + w;
                    if (MODE == 0) ob[o] = f2bf(acc[i][j][r]);
                    else of[o] += acc[i][j][r];
                }
            }
        }
}

// ---------------- fused attention v3 (unchanged) ----------------
__global__ __launch_bounds__(256, 2) void attn_fused(
    const unsigned short* __restrict__ qb, const unsigned short* __restrict__ kb,
    const unsigned short* __restrict__ vb, float* __restrict__ qko,
    unsigned short* __restrict__ abT) {
    __shared__ unsigned short Kl[512 * 32];
    __shared__ unsigned short Vl[32 * 512];
    __shared__ unsigned short Ql[64 * 32];
    const int bch = blockIdx.x, qt = blockIdx.y;
    const int bc = bch >> 3, h = bch & 7;
    const int tx = threadIdx.x;
    const int lane = tx & 63, wid = tx >> 6;
    const int lr = lane & 15, lg = lane >> 4;

    const unsigned short* kbase = kb + ((size_t)bc * FF + h * DH) * WW;
    const unsigned short* vbase = vb + ((size_t)bc * FF + h * DH) * WW;
    const unsigned short* qbase = qb + ((size_t)bc * FF + h * DH) * WW + qt * 64;

    {
        int d0 = ((tx >> 3) & 7) * 4;
#pragma unroll
        for (int rep = 0; rep < 2; ++rep) {
            int kw0 = (tx & 7) * 8 + ((tx >> 6) & 3) * 64 + rep * 256;
            us8 v0 = *(const us8*)(kbase + (size_t)(d0 + 0) * WW + kw0);
            us8 v1 = *(const us8*)(kbase + (size_t)(d0 + 1) * WW + kw0);
            us8 v2 = *(const us8*)(kbase + (size_t)(d0 + 2) * WW + kw0);
            us8 v3 = *(const us8*)(kbase + (size_t)(d0 + 3) * WW + kw0);
#pragma unroll
            for (int j = 0; j < 8; ++j) {
                int kw = kw0 + j;
                us4 p; p.x = v0[j]; p.y = v1[j]; p.z = v2[j]; p.w = v3[j];
                *(us4*)((char*)Kl + kw * 64 + ((d0 * 2) ^ ((kw & 3) << 4))) = p;
            }
        }
    }
    {
        int d = tx >> 3;
        int sw = (d & 7) << 4;
#pragma unroll
        for (int rep = 0; rep < 8; ++rep) {
            int kw0 = (tx & 7) * 8 + rep * 64;
            us8 tv = *(const us8*)(vbase + (size_t)d * WW + kw0);
            *(us8*)((char*)Vl + d * 1024 + ((kw0 * 2) ^ sw)) = tv;
        }
    }
    if (tx < 64) {
        int d0 = ((tx >> 3) & 7) * 4;
        int q0 = (tx & 7) * 8;
        us8 v0 = *(const us8*)(qbase + (size_t)(d0 + 0) * WW + q0);
        us8 v1 = *(const us8*)(qbase + (size_t)(d0 + 1) * WW + q0);
        us8 v2 = *(const us8*)(qbase + (size_t)(d0 + 2) * WW + q0);
        us8 v3 = *(const us8*)(qbase + (size_t)(d0 + 3) * WW + q0);
#pragma unroll
        for (int j = 0; j < 8; ++j) {
            us4 p; p.x = v0[j]; p.y = v1[j]; p.z = v2[j]; p.w = v3[j];
            *(us4*)(&Ql[(q0 + j) * 32 + d0]) = p;
        }
    }
    __syncthreads();

    const int q0w = wid * 16;
    bf16x8 qf = *(const bf16x8*)((char*)Ql + (q0w + lr) * 64 + lg * 16);
    f32x4 s[32];
#pragma unroll
    for (int i = 0; i < 32; ++i) s[i] = (f32x4){0.f, 0.f, 0.f, 0.f};
#pragma unroll
    for (int kwt = 0; kwt < 32; ++kwt) {
        int krow = kwt * 16 + lr;
        bf16x8 kf = *(const bf16x8*)((char*)Kl + krow * 64 + ((lg * 16) ^ ((krow & 3) << 4)));
        s[kwt] = mfma16(kf, qf, s[kwt]);
    }
    float mx = -3.0e38f;
    float* qrow = qko + ((size_t)bch * WW + qt * 64 + q0w + lr) * WW;
#pragma unroll
    for (int kwt = 0; kwt < 32; ++kwt) {
        s[kwt] *= 0.0625f;
        float4 st;
        st.x = s[kwt][0]; st.y = s[kwt][1]; st.z = s[kwt][2]; st.w = s[kwt][3];
        *(float4*)(qrow + kwt * 16 + lg * 4) = st;
        mx = fmaxf(mx, fmaxf(fmaxf(st.x, st.y), fmaxf(st.z, st.w)));
    }
    mx = fmaxf(mx, __shfl_xor(mx, 16));
    mx = fmaxf(mx, __shfl_xor(mx, 32));
    float sum = 0.f;
#pragma unroll
    for (int kwt = 0; kwt < 32; ++kwt) {
#pragma unroll
        for (int r = 0; r < 4; ++r) {
            float p = __expf(s[kwt][r] - mx);
            s[kwt][r] = p;
            sum += p;
        }
    }
    sum += __shfl_xor(sum, 16);
    sum += __shfl_xor(sum, 32);
    float inv = 1.0f / sum;

    f32x4 av[2];
    av[0] = (f32x4){0.f, 0.f, 0.f, 0.f};
    av[1] = (f32x4){0.f, 0.f, 0.f, 0.f};
#pragma unroll
    for (int t = 0; t < 16; ++t) {
        unsigned pa0 = f2bf(s[2 * t][0]) | ((unsigned)f2bf(s[2 * t][1]) << 16);
        unsigned pa1 = f2bf(s[2 * t][2]) | ((unsigned)f2bf(s[2 * t][3]) << 16);
        unsigned pb0 = f2bf(s[2 * t + 1][0]) | ((unsigned)f2bf(s[2 * t + 1][1]) << 16);
        unsigned pb1 = f2bf(s[2 * t + 1][2]) | ((unsigned)f2bf(s[2 * t + 1][3]) << 16);
        unsigned s16_0 = (lg == 1) ? pa0 : pb0, s16_1 = (lg == 1) ? pa1 : pb1;
        unsigned s32_0 = (lg == 3) ? pa0 : pb0, s32_1 = (lg == 3) ? pa1 : pb1;
        unsigned s48_0 = (lg == 2) ? pa0 : pb0, s48_1 = (lg == 2) ? pa1 : pb1;
        unsigned r16_0 = (unsigned)__shfl_xor((int)s16_0, 16);
        unsigned r16_1 = (unsigned)__shfl_xor((int)s16_1, 16);
        unsigned r32_0 = (unsigned)__shfl_xor((int)s32_0, 32);
        unsigned r32_1 = (unsigned)__shfl_xor((int)s32_1, 32);
        unsigned r48_0 = (unsigned)__shfl_xor((int)s48_0, 48);
        unsigned r48_1 = (unsigned)__shfl_xor((int)s48_1, 48);
        uint4 wv;
        if (lg == 0)      { wv.x = pa0;   wv.y = pa1;   wv.z = r16_0; wv.w = r16_1; }
        else if (lg == 1) { wv.x = r48_0; wv.y = r48_1; wv.z = r32_0; wv.w = r32_1; }
        else if (lg == 2) { wv.x = r32_0; wv.y = r32_1; wv.z = r48_0; wv.w = r48_1; }
        else              { wv.x = r16_0; wv.y = r16_1; wv.z = pb0;  wv.w = pb1; }
        bf16x8 pf = *reinterpret_cast<bf16x8*>(&wv);
#pragma unroll
        for (int di = 0; di < 2; ++di) {
            int vr = di * 16 + lr;
            bf16x8 vf = *(const bf16x8*)((char*)Vl + vr * 1024 + ((t * 64 + lg * 16) ^ ((vr & 7) << 4)));
            av[di] = mfma16(vf, pf, av[di]);
        }
    }
    unsigned short* arow = abT + ((size_t)bc * WW + qt * 64 + q0w + lr) * FF + h * DH;
#pragma unroll
    for (int di = 0; di < 2; ++di) {
        us4 pk;
        pk.x = f2bf(av[di][0] * inv); pk.y = f2bf(av[di][1] * inv);
        pk.z = f2bf(av[di][2] * inv); pk.w = f2bf(av[di][3] * inv);
        *(us4*)(arow + di * 16 + lg * 4) = pk;
    }
}

// ---------------- LDS-tiled depthwise 16-ch mix ----------------
template <int NPC, int MODE>
__global__ __launch_bounds__(256) void dwmix(
    const unsigned short* __restrict__ in, const float* __restrict__ wdw,
    const float* __restrict__ x, float* __restrict__ fo, unsigned short* __restrict__ bo) {
    __shared__ unsigned short L[16][1024];
    int b = blockIdx.y;
    size_t base = (size_t)blockIdx.x * 1024;
    int tx = threadIdx.x;
#pragma unroll
    for (int r = 0; r < 8; ++r) {
        int idx = tx + r * 256;
        int ci = idx >> 7;
        int seg = idx & 127;
        *(us8*)&L[ci][seg * 8] = *(const us8*)(in + ((size_t)(b * 16 + ci)) * NPC + base + seg * 8);
    }
    __syncthreads();
#pragma unroll
    for (int pos = 0; pos < 4; ++pos) {
        int fw = tx + pos * 256;
        float vin[16];
#pragma unroll
        for (int ci = 0; ci < 16; ++ci) vin[ci] = bf2f(L[ci][fw]);
#pragma unroll
        for (int o = 0; o < 16; ++o) {
            float s = 0.f;
#pragma unroll
            for (int ci = 0; ci < 16; ++ci) s += wdw[o * 16 + ci] * vin[ci];
            size_t oi = ((size_t)(b * 16 + o)) * NPC + base + fw;
            if (MODE == 0) fo[oi] = x[oi] + s;
            else { s = fmaxf(s, 0.f); bo[oi] = f2bf(s * s); }
        }
    }
}

extern "C" void kernel_launch(void* const* d_in, const int* in_sizes, int n_in,
                              void* d_out, int out_size, void* d_ws, size_t ws_size,
                              hipStream_t stream) {
    const float* x      = (const float*)d_in[0];
    const float* conv_q = (const float*)d_in[1];
    const float* conv_k = (const float*)d_in[2];
    const float* conv_v = (const float*)d_in[3];
    const float* wq     = (const float*)d_in[4];
    const float* wk     = (const float*)d_in[5];
    const float* wv     = (const float*)d_in[6];
    const float* wo_pw  = (const float*)d_in[7];
    const float* wo_dw  = (const float*)d_in[8];
    const float* g1     = (const float*)d_in[9];
    const float* b1     = (const float*)d_in[10];
    const float* g2     = (const float*)d_in[11];
    const float* b2     = (const float*)d_in[12];
    const float* w1_pw  = (const float*)d_in[13];
    const float* w1_dw  = (const float*)d_in[14];
    const float* w2_pw  = (const float*)d_in[15];

    float* hout  = (float*)d_out;
    float* qkout = (float*)d_out + 4194304;

    char* ws = (char*)d_ws;
    const size_t MB1 = (size_t)1 << 20;
    const size_t MB8 = (size_t)8 << 20;
    unsigned short* n1  = (unsigned short*)(ws + 0 * MB8);   // later: abT
    unsigned short* cq  = (unsigned short*)(ws + 1 * MB8);   // later: pwb
    unsigned short* ck  = (unsigned short*)(ws + 2 * MB8);   // later: n2t
    unsigned short* cv  = (unsigned short*)(ws + 3 * MB8);
    unsigned short* qb  = (unsigned short*)(ws + 4 * MB8);
    unsigned short* kb  = (unsigned short*)(ws + 5 * MB8);
    unsigned short* vb  = (unsigned short*)(ws + 6 * MB8);
    unsigned short* u1t = (unsigned short*)(ws + 3 * MB8);   // 32 MB (cv/qb/kb/vb dead)
    unsigned short* u2t = (unsigned short*)(ws + 7 * MB8);   // 32 MB (weights dead by then)
    // bf16 weights in the [7..10] region (dead once dwsq writes u2t there)
    unsigned short* Wq16 = (unsigned short*)(ws + 7 * MB8 + 0 * MB1);   // 2 MB
    unsigned short* Wk16 = (unsigned short*)(ws + 7 * MB8 + 2 * MB1);
    unsigned short* Wv16 = (unsigned short*)(ws + 7 * MB8 + 4 * MB1);
    unsigned short* Wo16 = (unsigned short*)(ws + 7 * MB8 + 6 * MB1);
    unsigned short* W116 = (unsigned short*)(ws + 7 * MB8 + 8 * MB1);   // 8 MB
    unsigned short* Awb  = (unsigned short*)(ws + 7 * MB8 + 16 * MB1);  // 15 KB
    unsigned short* W216 = (unsigned short*)(ws + 3 * MB8);             // 8 MB, after dwsq (u1t dead)
    unsigned short* abT = n1;
    unsigned short* pwb = cq;
    unsigned short* n2t = ck;

    ln_kernel<<<dim3(BC, 2), 256, 0, stream>>>(x, g1, b1, n1);
    wrepack<<<dim3(30), 256, 0, stream>>>(conv_q, conv_k, conv_v, Awb);
    cvt_bf16<<<dim3(512), 256, 0, stream>>>(wq, Wq16, 131072);
    cvt_bf16<<<dim3(512), 256, 0, stream>>>(wk, Wk16, 131072);
    cvt_bf16<<<dim3(512), 256, 0, stream>>>(wv, Wv16, 131072);
    cvt_bf16<<<dim3(512), 256, 0, stream>>>(wo_pw, Wo16, 131072);
    cvt_bf16<<<dim3(2048), 256, 0, stream>>>(w1_pw, W116, 524288);
    conv3_mfma<<<dim3(8, 64, BB), 256, 0, stream>>>(n1, Awb, cq, ck, cv);
    mgemm2<256, 256, 1, 0><<<dim3(BC, 2, 4), 256, 0, stream>>>(Wq16, cq, qb, nullptr);
    mgemm2<256, 256, 1, 0><<<dim3(BC, 2, 4), 256, 0, stream>>>(Wk16, ck, kb, nullptr);
    mgemm2<256, 256, 1, 0><<<dim3(BC, 2, 4), 256, 0, stream>>>(Wv16, cv, vb, nullptr);
    attn_fused<<<dim3(BC * HH, 8), 256, 0, stream>>>(qb, kb, vb, qkout, abT);
    mgemm2<256, 256, 0, 0><<<dim3(BC, 2, 4), 256, 0, stream>>>(Wo16, abT, pwb, nullptr);
    dwmix<131072, 0><<<dim3(128, BB), 256, 0, stream>>>(pwb, wo_dw, x, hout, nullptr);
    ln_t_kernel<<<dim3(BC, 2), 256, 0, stream>>>(hout, g2, b2, n2t);
    mgemm2<256, 1024, 0, 2><<<dim3(BC, 8, 4), 256, 0, stream>>>(W116, n2t, u1t, nullptr);
    dwmix<524288, 1><<<dim3(512, BB), 256, 0, stream>>>(u1t, w1_dw, nullptr, nullptr, u2t);
    cvt_bf16<<<dim3(2048), 256, 0, stream>>>(w2_pw, W216, 524288);
    mgemm2<1024, 256, 0, 1><<<dim3(BC, 2, 4), 256, 0, stream>>>(W216, u2t, nullptr, hout);
}

// Round 7
// 337.482 us; speedup vs baseline: 1.1166x; 1.1166x over previous
//
#include <hip/hip_runtime.h>

#define BB 2
#define CC 16
#define BC 32
#define FF 256
#define WW 512
#define HH 8
#define DH 32

using bf16x8 = __attribute__((ext_vector_type(8))) __bf16;
using f32x4  = __attribute__((ext_vector_type(4))) float;
using us8    = __attribute__((ext_vector_type(8))) unsigned short;
using us4    = __attribute__((ext_vector_type(4))) unsigned short;

__device__ __forceinline__ float bf2f(unsigned short u) {
    union { unsigned int i; float f; } x; x.i = ((unsigned int)u) << 16; return x.f;
}
__device__ __forceinline__ unsigned short f2bf(float f) {
    union { float f; unsigned int i; } x; x.f = f;
    unsigned int r = x.i + 0x7fffu + ((x.i >> 16) & 1u);   // round-nearest-even
    return (unsigned short)(r >> 16);
}
__device__ __forceinline__ f32x4 mfma16(bf16x8 a, bf16x8 b, f32x4 c) {
    return __builtin_amdgcn_mfma_f32_16x16x32_bf16(a, b, c, 0, 0, 0);
}

// ---------------- fused f32 -> bf16 weight convert (wq,wk,wv,wo,w1) ----------------
__global__ __launch_bounds__(256) void cvt5(
    const float* __restrict__ s0, const float* __restrict__ s1,
    const float* __restrict__ s2, const float* __restrict__ s3,
    const float* __restrict__ s4,
    unsigned short* __restrict__ d0, unsigned short* __restrict__ d1,
    unsigned short* __restrict__ d2, unsigned short* __restrict__ d3,
    unsigned short* __restrict__ d4) {
    int i = blockIdx.x * 256 + threadIdx.x;   // < 4*131072 + 524288
    const float* s; unsigned short* d; int off;
    if (i < 131072)       { s = s0; d = d0; off = i; }
    else if (i < 262144)  { s = s1; d = d1; off = i - 131072; }
    else if (i < 393216)  { s = s2; d = d2; off = i - 262144; }
    else if (i < 524288)  { s = s3; d = d3; off = i - 393216; }
    else                  { s = s4; d = d4; off = i - 524288; }
    const float4* sp = (const float4*)s + (size_t)off * 2;
    float4 a = sp[0], b = sp[1];
    us8 p;
    p[0] = f2bf(a.x); p[1] = f2bf(a.y); p[2] = f2bf(a.z); p[3] = f2bf(a.w);
    p[4] = f2bf(b.x); p[5] = f2bf(b.y); p[6] = f2bf(b.z); p[7] = f2bf(b.w);
    *((us8*)d + off) = p;
}

__global__ __launch_bounds__(256) void cvt_bf16(
    const float* __restrict__ src, unsigned short* __restrict__ dst, int n8) {
    int i = blockIdx.x * 256 + threadIdx.x;
    if (i >= n8) return;
    const float4* s = (const float4*)src + (size_t)i * 2;
    float4 a = s[0], b = s[1];
    us8 p;
    p[0] = f2bf(a.x); p[1] = f2bf(a.y); p[2] = f2bf(a.z); p[3] = f2bf(a.w);
    p[4] = f2bf(b.x); p[5] = f2bf(b.y); p[6] = f2bf(b.z); p[7] = f2bf(b.w);
    *((us8*)dst + i) = p;
}

// ---------------- LayerNorm over f -> [f][w] bf16 ----------------
__global__ __launch_bounds__(256) void ln_kernel(
    const float* __restrict__ x, const float* __restrict__ g,
    const float* __restrict__ bta, unsigned short* __restrict__ out) {
    int bc = blockIdx.x;
    int c = bc & (CC - 1);
    int w = blockIdx.y * 256 + threadIdx.x;
    const float* xp = x + ((size_t)bc * FF) * WW + w;
    float s = 0.f, s2 = 0.f;
#pragma unroll 4
    for (int f = 0; f < FF; ++f) { float t = xp[(size_t)f * WW]; s += t; s2 += t * t; }
    float m = s * (1.f / FF);
    float v = s2 * (1.f / FF) - m * m;
    float r = rsqrtf(v + 1e-5f);
    unsigned short* op = out + ((size_t)bc * FF) * WW + w;
    const float* gp = g + c * FF;
    const float* bp = bta + c * FF;
#pragma unroll 4
    for (int f = 0; f < FF; ++f) {
        float t = (xp[(size_t)f * WW] - m) * r * gp[f] + bp[f];
        op[(size_t)f * WW] = f2bf(t);
    }
}

// ---------------- LayerNorm over f -> TRANSPOSED [w][f] bf16 ----------------
__global__ __launch_bounds__(256) void ln_t_kernel(
    const float* __restrict__ x, const float* __restrict__ g,
    const float* __restrict__ bta, unsigned short* __restrict__ out) {
    int bc = blockIdx.x;
    int c = bc & (CC - 1);
    int w = blockIdx.y * 256 + threadIdx.x;
    const float* xp = x + ((size_t)bc * FF) * WW + w;
    float s = 0.f, s2 = 0.f;
#pragma unroll 4
    for (int f = 0; f < FF; ++f) { float t = xp[(size_t)f * WW]; s += t; s2 += t * t; }
    float m = s * (1.f / FF);
    float v = s2 * (1.f / FF) - m * m;
    float r = rsqrtf(v + 1e-5f);
    unsigned short* op = out + ((size_t)bc * WW + w) * FF;
    const float* gp = g + c * FF;
    const float* bp = bta + c * FF;
    for (int f8 = 0; f8 < FF / 8; ++f8) {
        us8 pk;
#pragma unroll
        for (int e = 0; e < 8; ++e) {
            int f = f8 * 8 + e;
            float t = (xp[(size_t)f * WW] - m) * r * gp[f] + bp[f];
            pk[e] = f2bf(t);
        }
        *(us8*)(op + f8 * 8) = pk;
    }
}

// ---------------- conv weight repack ----------------
__global__ __launch_bounds__(256) void wrepack(
    const float* __restrict__ wq, const float* __restrict__ wk, const float* __restrict__ wv,
    unsigned short* __restrict__ Aw) {
    int idx = blockIdx.x * 256 + threadIdx.x;   // < 3*2560
    int tensor = idx / 2560;
    int r = idx - tensor * 2560;
    int tp = r >> 9, co = (r >> 5) & 15, k = r & 31;
    int tap = tp * 2 + (k >> 4), ci = k & 15;
    float v = 0.f;
    if (tap < 9) {
        const float* w = tensor == 0 ? wq : (tensor == 1 ? wk : wv);
        v = w[(co * 16 + ci) * 9 + tap];
    }
    Aw[idx] = f2bf(v);
}

// ---------------- MFMA conv3x3 ----------------
__global__ __launch_bounds__(256) void conv3_mfma(
    const unsigned short* __restrict__ n1, const unsigned short* __restrict__ Aw,
    unsigned short* __restrict__ oq, unsigned short* __restrict__ ok,
    unsigned short* __restrict__ ov) {
    __shared__ __align__(16) unsigned short Xl[6][68][16];
    const int b = blockIdx.z;
    const int f0 = blockIdx.y * 4;
    const int w0 = blockIdx.x * 64;
    const int tx = threadIdx.x;
    const int lane = tx & 63, wid = tx >> 6;
    const int lr = lane & 15, lg = lane >> 4;
    {
        uint4 z{0, 0, 0, 0};
        for (int i = tx; i < 816; i += 256) ((uint4*)Xl)[i] = z;
    }
    __syncthreads();
    for (int task = tx; task < 960; task += 256) {
        int c = task % 10;
        int fr = (task / 10) % 6;
        int ci = task / 60;
        int fy = f0 - 1 + fr;
        int wx = w0 - 8 + c * 8;
        if (fy >= 0 && fy < FF && wx >= 0 && wx <= WW - 8) {
            us8 v = *(const us8*)(n1 + ((size_t)(b * CC + ci) * FF + fy) * WW + wx);
#pragma unroll
            for (int e = 0; e < 8; ++e) {
                int wl = c * 8 + e - 7;
                if (wl >= 0 && wl < 66) Xl[fr][wl][ci] = v[e];
            }
        }
    }
    __syncthreads();
    bf16x8 A[3][5];
#pragma unroll
    for (int t3 = 0; t3 < 3; ++t3)
#pragma unroll
        for (int t = 0; t < 5; ++t)
            A[t3][t] = *(const bf16x8*)(Aw + ((t3 * 5 + t) * 16 + lr) * 32 + lg * 8);
    const bool h = (lane & 32) != 0;
    int doff[5];
    doff[0] = (h ? (-68 * 32) : ((-68 - 1) * 32));
    doff[1] = (h ? (-1 * 32) : ((-68 + 1) * 32));
    doff[2] = (h ? (1 * 32) : 0);
    doff[3] = (h ? (68 * 32) : ((68 - 1) * 32));
    doff[4] = ((68 + 1) * 32);
    const int fl = wid + 1;
    const int fglob = f0 + wid;
    char* xbase = (char*)Xl + (fl * 68 + 1) * 32 + ((lg & 1) ? 16 : 0);
#pragma unroll
    for (int pt = 0; pt < 4; ++pt) {
        char* bb = xbase + (pt * 16 + lr) * 32;
        bf16x8 Bf[5];
#pragma unroll
        for (int t = 0; t < 5; ++t) Bf[t] = *(const bf16x8*)(bb + doff[t]);
        f32x4 aq = {0.f, 0.f, 0.f, 0.f}, ak = {0.f, 0.f, 0.f, 0.f}, av = {0.f, 0.f, 0.f, 0.f};
#pragma unroll
        for (int t = 0; t < 5; ++t) {
            aq = mfma16(A[0][t], Bf[t], aq);
            ak = mfma16(A[1][t], Bf[t], ak);
            av = mfma16(A[2][t], Bf[t], av);
        }
        int w = w0 + pt * 16 + lr;
#pragma unroll
        for (int r = 0; r < 4; ++r) {
            int co = lg * 4 + r;
            size_t o = ((size_t)(b * CC + co) * FF + fglob) * WW + w;
            oq[o] = f2bf(aq[r]);
            ok[o] = f2bf(ak[r]);
            ov[o] = f2bf(av[r]);
        }
    }
}

// ---------------- 128x128-tile MFMA GEMM (FFN-up) ----------------
template <int K, int M, int BSRC, int MODE>
__global__ __launch_bounds__(256, 2) void mgemm2(
    const unsigned short* __restrict__ Wb, const unsigned short* __restrict__ T,
    unsigned short* __restrict__ ob, float* __restrict__ of) {
    __shared__ __align__(16) unsigned short Al[128 * 64];
    __shared__ __align__(16) unsigned short Bl[128 * 64];
    const int bc = blockIdx.x, c = bc & 15;
    const int G0 = blockIdx.y * 128, W0 = blockIdx.z * 128;
    const int tx = threadIdx.x;
    const int lane = tx & 63, wid = tx >> 6;
    const int lr = lane & 15, lg = lane >> 4;
    const int wr = wid >> 1, wc = wid & 1;
    const unsigned short* Ab = Wb + ((size_t)c * M + G0) * K;
    f32x4 acc[4][4];
#pragma unroll
    for (int i = 0; i < 4; ++i)
#pragma unroll
        for (int j = 0; j < 4; ++j) acc[i][j] = (f32x4){0.f, 0.f, 0.f, 0.f};

    for (int f0 = 0; f0 < K; f0 += 64) {
#pragma unroll
        for (int rep = 0; rep < 4; ++rep) {
            int idx = tx + rep * 256;
            int row = idx >> 3, seg = idx & 7;
            us8 v = *(const us8*)(Ab + (size_t)row * K + f0 + seg * 8);
            *(us8*)((char*)Al + row * 128 + ((seg ^ (row & 7)) << 4)) = v;
        }
        if (BSRC == 0) {
            const unsigned short* Tb = T + ((size_t)bc * WW + W0) * K;
#pragma unroll
            for (int rep = 0; rep < 4; ++rep) {
                int idx = tx + rep * 256;
                int row = idx >> 3, seg = idx & 7;
                us8 v = *(const us8*)(Tb + (size_t)row * K + f0 + seg * 8);
                *(us8*)((char*)Bl + row * 128 +
                        ((seg ^ (row & 7) ^ ((row >> 3) & 7)) << 4)) = v;
            }
        } else {
            const unsigned short* Tb = T + (size_t)bc * K * WW;
            const int wseg = tx & 15, fgrp = tx >> 4;
            us8 tv[4];
#pragma unroll
            for (int i = 0; i < 4; ++i)
                tv[i] = *(const us8*)(Tb + (size_t)(f0 + fgrp * 4 + i) * WW + W0 + wseg * 8);
#pragma unroll
            for (int j = 0; j < 8; ++j) {
                int w = wseg * 8 + j;
                us4 p; p.x = tv[0][j]; p.y = tv[1][j]; p.z = tv[2][j]; p.w = tv[3][j];
                *(us4*)((char*)Bl + w * 128 +
                        ((((fgrp >> 1) ^ (w & 7) ^ ((w >> 3) & 7)) << 4)) + (fgrp & 1) * 8) = p;
            }
        }
        __syncthreads();
#pragma unroll
        for (int kc = 0; kc < 2; ++kc) {
            bf16x8 af[4], bf[4];
#pragma unroll
            for (int i = 0; i < 4; ++i) {
                int gr = wr * 64 + i * 16 + lr;
                af[i] = *(const bf16x8*)((char*)Al + gr * 128 +
                        (((kc * 4 + lg) ^ (gr & 7)) << 4));
                int wrw = wc * 64 + i * 16 + lr;
                bf[i] = *(const bf16x8*)((char*)Bl + wrw * 128 +
                        (((kc * 4 + lg) ^ (wrw & 7) ^ ((wrw >> 3) & 7)) << 4));
            }
#pragma unroll
            for (int i = 0; i < 4; ++i)
#pragma unroll
                for (int j = 0; j < 4; ++j)
                    acc[i][j] = mfma16(af[i], bf[j], acc[i][j]);
        }
        __syncthreads();
    }
#pragma unroll
    for (int i = 0; i < 4; ++i)
#pragma unroll
        for (int j = 0; j < 4; ++j) {
            int g = G0 + wr * 64 + i * 16 + lg * 4;
            int w = W0 + wc * 64 + j * 16 + lr;
            if (MODE == 2) {
                us4 pk;
                pk.x = f2bf(acc[i][j][0]); pk.y = f2bf(acc[i][j][1]);
                pk.z = f2bf(acc[i][j][2]); pk.w = f2bf(acc[i][j][3]);
                *(us4*)(ob + ((size_t)bc * WW + w) * M + g) = pk;
            } else {
#pragma unroll
                for (int r = 0; r < 4; ++r) {
                    size_t o = ((size_t)bc * M + g + r) * WW + w;
                    if (MODE == 0) ob[o] = f2bf(acc[i][j][r]);
                    else of[o] += acc[i][j][r];
                }
            }
        }
}

// ---------------- 64x128-tile MFMA GEMM (M=256 cases): 3 blocks/CU ----------------
template <int K, int M, int BSRC, int MODE>
__global__ __launch_bounds__(256, 3) void mgemm3(
    const unsigned short* __restrict__ Wb, const unsigned short* __restrict__ T,
    unsigned short* __restrict__ ob, float* __restrict__ of) {
    __shared__ __align__(16) unsigned short Al[64 * 64];
    __shared__ __align__(16) unsigned short Bl[128 * 64];
    const int bc = blockIdx.x, c = bc & 15;
    const int G0 = blockIdx.y * 64, W0 = blockIdx.z * 128;
    const int tx = threadIdx.x;
    const int lane = tx & 63, wid = tx >> 6;
    const int lr = lane & 15, lg = lane >> 4;
    const int wr = wid >> 1, wc = wid & 1;
    const unsigned short* Ab = Wb + ((size_t)c * M + G0) * K;
    f32x4 acc[2][4];
#pragma unroll
    for (int i = 0; i < 2; ++i)
#pragma unroll
        for (int j = 0; j < 4; ++j) acc[i][j] = (f32x4){0.f, 0.f, 0.f, 0.f};

    for (int f0 = 0; f0 < K; f0 += 64) {
        // stage A (64 g x 64 k)
#pragma unroll
        for (int rep = 0; rep < 2; ++rep) {
            int idx = tx + rep * 256;
            int row = idx >> 3, seg = idx & 7;
            us8 v = *(const us8*)(Ab + (size_t)row * K + f0 + seg * 8);
            *(us8*)((char*)Al + row * 128 + ((seg ^ (row & 7)) << 4)) = v;
        }
        // stage B (128 w x 64 k)
        if (BSRC == 0) {
            const unsigned short* Tb = T + ((size_t)bc * WW + W0) * K;
#pragma unroll
            for (int rep = 0; rep < 4; ++rep) {
                int idx = tx + rep * 256;
                int row = idx >> 3, seg = idx & 7;
                us8 v = *(const us8*)(Tb + (size_t)row * K + f0 + seg * 8);
                *(us8*)((char*)Bl + row * 128 +
                        ((seg ^ (row & 7) ^ ((row >> 3) & 7)) << 4)) = v;
            }
        } else {
            const unsigned short* Tb = T + (size_t)bc * K * WW;
            const int wseg = tx & 15, fgrp = tx >> 4;
            us8 tv[4];
#pragma unroll
            for (int i = 0; i < 4; ++i)
                tv[i] = *(const us8*)(Tb + (size_t)(f0 + fgrp * 4 + i) * WW + W0 + wseg * 8);
#pragma unroll
            for (int j = 0; j < 8; ++j) {
                int w = wseg * 8 + j;
                us4 p; p.x = tv[0][j]; p.y = tv[1][j]; p.z = tv[2][j]; p.w = tv[3][j];
                *(us4*)((char*)Bl + w * 128 +
                        ((((fgrp >> 1) ^ (w & 7) ^ ((w >> 3) & 7)) << 4)) + (fgrp & 1) * 8) = p;
            }
        }
        __syncthreads();
#pragma unroll
        for (int kc = 0; kc < 2; ++kc) {
            bf16x8 af[2], bf[4];
#pragma unroll
            for (int i = 0; i < 2; ++i) {
                int gr = wr * 32 + i * 16 + lr;
                af[i] = *(const bf16x8*)((char*)Al + gr * 128 +
                        (((kc * 4 + lg) ^ (gr & 7)) << 4));
            }
#pragma unroll
            for (int j = 0; j < 4; ++j) {
                int wrw = wc * 64 + j * 16 + lr;
                bf[j] = *(const bf16x8*)((char*)Bl + wrw * 128 +
                        (((kc * 4 + lg) ^ (wrw & 7) ^ ((wrw >> 3) & 7)) << 4));
            }
#pragma unroll
            for (int i = 0; i < 2; ++i)
#pragma unroll
                for (int j = 0; j < 4; ++j)
                    acc[i][j] = mfma16(af[i], bf[j], acc[i][j]);
        }
        __syncthreads();
    }
#pragma unroll
    for (int i = 0; i < 2; ++i)
#pragma unroll
        for (int j = 0; j < 4; ++j) {
            int g = G0 + wr * 32 + i * 16 + lg * 4;
            int w = W0 + wc * 64 + j * 16 + lr;
            if (MODE == 2) {
                us4 pk;
                pk.x = f2bf(acc[i][j][0]); pk.y = f2bf(acc[i][j][1]);
                pk.z = f2bf(acc[i][j][2]); pk.w = f2bf(acc[i][j][3]);
                *(us4*)(ob + ((size_t)bc * WW + w) * M + g) = pk;
            } else {
#pragma unroll
                for (int r = 0; r < 4; ++r) {
                    size_t o = ((size_t)bc * M + g + r) * WW + w;
                    if (MODE == 0) ob[o] = f2bf(acc[i][j][r]);
                    else of[o] += acc[i][j][r];
                }
            }
        }
}

// ---------------- fused attention v3 (unchanged) ----------------
__global__ __launch_bounds__(256, 2) void attn_fused(
    const unsigned short* __restrict__ qb, const unsigned short* __restrict__ kb,
    const unsigned short* __restrict__ vb, float* __restrict__ qko,
    unsigned short* __restrict__ abT) {
    __shared__ unsigned short Kl[512 * 32];
    __shared__ unsigned short Vl[32 * 512];
    __shared__ unsigned short Ql[64 * 32];
    const int bch = blockIdx.x, qt = blockIdx.y;
    const int bc = bch >> 3, h = bch & 7;
    const int tx = threadIdx.x;
    const int lane = tx & 63, wid = tx >> 6;
    const int lr = lane & 15, lg = lane >> 4;

    const unsigned short* kbase = kb + ((size_t)bc * FF + h * DH) * WW;
    const unsigned short* vbase = vb + ((size_t)bc * FF + h * DH) * WW;
    const unsigned short* qbase = qb + ((size_t)bc * FF + h * DH) * WW + qt * 64;

    {
        int d0 = ((tx >> 3) & 7) * 4;
#pragma unroll
        for (int rep = 0; rep < 2; ++rep) {
            int kw0 = (tx & 7) * 8 + ((tx >> 6) & 3) * 64 + rep * 256;
            us8 v0 = *(const us8*)(kbase + (size_t)(d0 + 0) * WW + kw0);
            us8 v1 = *(const us8*)(kbase + (size_t)(d0 + 1) * WW + kw0);
            us8 v2 = *(const us8*)(kbase + (size_t)(d0 + 2) * WW + kw0);
            us8 v3 = *(const us8*)(kbase + (size_t)(d0 + 3) * WW + kw0);
#pragma unroll
            for (int j = 0; j < 8; ++j) {
                int kw = kw0 + j;
                us4 p; p.x = v0[j]; p.y = v1[j]; p.z = v2[j]; p.w = v3[j];
                *(us4*)((char*)Kl + kw * 64 + ((d0 * 2) ^ ((kw & 3) << 4))) = p;
            }
        }
    }
    {
        int d = tx >> 3;
        int sw = (d & 7) << 4;
#pragma unroll
        for (int rep = 0; rep < 8; ++rep) {
            int kw0 = (tx & 7) * 8 + rep * 64;
            us8 tv = *(const us8*)(vbase + (size_t)d * WW + kw0);
            *(us8*)((char*)Vl + d * 1024 + ((kw0 * 2) ^ sw)) = tv;
        }
    }
    if (tx < 64) {
        int d0 = ((tx >> 3) & 7) * 4;
        int q0 = (tx & 7) * 8;
        us8 v0 = *(const us8*)(qbase + (size_t)(d0 + 0) * WW + q0);
        us8 v1 = *(const us8*)(qbase + (size_t)(d0 + 1) * WW + q0);
        us8 v2 = *(const us8*)(qbase + (size_t)(d0 + 2) * WW + q0);
        us8 v3 = *(const us8*)(qbase + (size_t)(d0 + 3) * WW + q0);
#pragma unroll
        for (int j = 0; j < 8; ++j) {
            us4 p; p.x = v0[j]; p.y = v1[j]; p.z = v2[j]; p.w = v3[j];
            *(us4*)(&Ql[(q0 + j) * 32 + d0]) = p;
        }
    }
    __syncthreads();

    const int q0w = wid * 16;
    bf16x8 qf = *(const bf16x8*)((char*)Ql + (q0w + lr) * 64 + lg * 16);
    f32x4 s[32];
#pragma unroll
    for (int i = 0; i < 32; ++i) s[i] = (f32x4){0.f, 0.f, 0.f, 0.f};
#pragma unroll
    for (int kwt = 0; kwt < 32; ++kwt) {
        int krow = kwt * 16 + lr;
        bf16x8 kf = *(const bf16x8*)((char*)Kl + krow * 64 + ((lg * 16) ^ ((krow & 3) << 4)));
        s[kwt] = mfma16(kf, qf, s[kwt]);
    }
    float mx = -3.0e38f;
    float* qrow = qko + ((size_t)bch * WW + qt * 64 + q0w + lr) * WW;
#pragma unroll
    for (int kwt = 0; kwt < 32; ++kwt) {
        s[kwt] *= 0.0625f;
        float4 st;
        st.x = s[kwt][0]; st.y = s[kwt][1]; st.z = s[kwt][2]; st.w = s[kwt][3];
        *(float4*)(qrow + kwt * 16 + lg * 4) = st;
        mx = fmaxf(mx, fmaxf(fmaxf(st.x, st.y), fmaxf(st.z, st.w)));
    }
    mx = fmaxf(mx, __shfl_xor(mx, 16));
    mx = fmaxf(mx, __shfl_xor(mx, 32));
    float sum = 0.f;
#pragma unroll
    for (int kwt = 0; kwt < 32; ++kwt) {
#pragma unroll
        for (int r = 0; r < 4; ++r) {
            float p = __expf(s[kwt][r] - mx);
            s[kwt][r] = p;
            sum += p;
        }
    }
    sum += __shfl_xor(sum, 16);
    sum += __shfl_xor(sum, 32);
    float inv = 1.0f / sum;

    f32x4 av[2];
    av[0] = (f32x4){0.f, 0.f, 0.f, 0.f};
    av[1] = (f32x4){0.f, 0.f, 0.f, 0.f};
#pragma unroll
    for (int t = 0; t < 16; ++t) {
        unsigned pa0 = f2bf(s[2 * t][0]) | ((unsigned)f2bf(s[2 * t][1]) << 16);
        unsigned pa1 = f2bf(s[2 * t][2]) | ((unsigned)f2bf(s[2 * t][3]) << 16);
        unsigned pb0 = f2bf(s[2 * t + 1][0]) | ((unsigned)f2bf(s[2 * t + 1][1]) << 16);
        unsigned pb1 = f2bf(s[2 * t + 1][2]) | ((unsigned)f2bf(s[2 * t + 1][3]) << 16);
        unsigned s16_0 = (lg == 1) ? pa0 : pb0, s16_1 = (lg == 1) ? pa1 : pb1;
        unsigned s32_0 = (lg == 3) ? pa0 : pb0, s32_1 = (lg == 3) ? pa1 : pb1;
        unsigned s48_0 = (lg == 2) ? pa0 : pb0, s48_1 = (lg == 2) ? pa1 : pb1;
        unsigned r16_0 = (unsigned)__shfl_xor((int)s16_0, 16);
        unsigned r16_1 = (unsigned)__shfl_xor((int)s16_1, 16);
        unsigned r32_0 = (unsigned)__shfl_xor((int)s32_0, 32);
        unsigned r32_1 = (unsigned)__shfl_xor((int)s32_1, 32);
        unsigned r48_0 = (unsigned)__shfl_xor((int)s48_0, 48);
        unsigned r48_1 = (unsigned)__shfl_xor((int)s48_1, 48);
        uint4 wv;
        if (lg == 0)      { wv.x = pa0;   wv.y = pa1;   wv.z = r16_0; wv.w = r16_1; }
        else if (lg == 1) { wv.x = r48_0; wv.y = r48_1; wv.z = r32_0; wv.w = r32_1; }
        else if (lg == 2) { wv.x = r32_0; wv.y = r32_1; wv.z = r48_0; wv.w = r48_1; }
        else              { wv.x = r16_0; wv.y = r16_1; wv.z = pb0;  wv.w = pb1; }
        bf16x8 pf = *reinterpret_cast<bf16x8*>(&wv);
#pragma unroll
        for (int di = 0; di < 2; ++di) {
            int vr = di * 16 + lr;
            bf16x8 vf = *(const bf16x8*)((char*)Vl + vr * 1024 + ((t * 64 + lg * 16) ^ ((vr & 7) << 4)));
            av[di] = mfma16(vf, pf, av[di]);
        }
    }
    unsigned short* arow = abT + ((size_t)bc * WW + qt * 64 + q0w + lr) * FF + h * DH;
#pragma unroll
    for (int di = 0; di < 2; ++di) {
        us4 pk;
        pk.x = f2bf(av[di][0] * inv); pk.y = f2bf(av[di][1] * inv);
        pk.z = f2bf(av[di][2] * inv); pk.w = f2bf(av[di][3] * inv);
        *(us4*)(arow + di * 16 + lg * 4) = pk;
    }
}

// ---------------- LDS-tiled depthwise 16-ch mix ----------------
template <int NPC, int MODE>
__global__ __launch_bounds__(256) void dwmix(
    const unsigned short* __restrict__ in, const float* __restrict__ wdw,
    const float* __restrict__ x, float* __restrict__ fo, unsigned short* __restrict__ bo) {
    __shared__ unsigned short L[16][1024];
    int b = blockIdx.y;
    size_t base = (size_t)blockIdx.x * 1024;
    int tx = threadIdx.x;
#pragma unroll
    for (int r = 0; r < 8; ++r) {
        int idx = tx + r * 256;
        int ci = idx >> 7;
        int seg = idx & 127;
        *(us8*)&L[ci][seg * 8] = *(const us8*)(in + ((size_t)(b * 16 + ci)) * NPC + base + seg * 8);
    }
    __syncthreads();
#pragma unroll
    for (int pos = 0; pos < 4; ++pos) {
        int fw = tx + pos * 256;
        float vin[16];
#pragma unroll
        for (int ci = 0; ci < 16; ++ci) vin[ci] = bf2f(L[ci][fw]);
#pragma unroll
        for (int o = 0; o < 16; ++o) {
            float s = 0.f;
#pragma unroll
            for (int ci = 0; ci < 16; ++ci) s += wdw[o * 16 + ci] * vin[ci];
            size_t oi = ((size_t)(b * 16 + o)) * NPC + base + fw;
            if (MODE == 0) fo[oi] = x[oi] + s;
            else { s = fmaxf(s, 0.f); bo[oi] = f2bf(s * s); }
        }
    }
}

extern "C" void kernel_launch(void* const* d_in, const int* in_sizes, int n_in,
                              void* d_out, int out_size, void* d_ws, size_t ws_size,
                              hipStream_t stream) {
    const float* x      = (const float*)d_in[0];
    const float* conv_q = (const float*)d_in[1];
    const float* conv_k = (const float*)d_in[2];
    const float* conv_v = (const float*)d_in[3];
    const float* wq     = (const float*)d_in[4];
    const float* wk     = (const float*)d_in[5];
    const float* wv     = (const float*)d_in[6];
    const float* wo_pw  = (const float*)d_in[7];
    const float* wo_dw  = (const float*)d_in[8];
    const float* g1     = (const float*)d_in[9];
    const float* b1     = (const float*)d_in[10];
    const float* g2     = (const float*)d_in[11];
    const float* b2     = (const float*)d_in[12];
    const float* w1_pw  = (const float*)d_in[13];
    const float* w1_dw  = (const float*)d_in[14];
    const float* w2_pw  = (const float*)d_in[15];

    float* hout  = (float*)d_out;
    float* qkout = (float*)d_out + 4194304;

    char* ws = (char*)d_ws;
    const size_t MB1 = (size_t)1 << 20;
    const size_t MB8 = (size_t)8 << 20;
    unsigned short* n1  = (unsigned short*)(ws + 0 * MB8);   // later: abT, then W216
    unsigned short* cq  = (unsigned short*)(ws + 1 * MB8);   // later: pwb
    unsigned short* ck  = (unsigned short*)(ws + 2 * MB8);   // later: n2t
    unsigned short* cv  = (unsigned short*)(ws + 3 * MB8);
    unsigned short* qb  = (unsigned short*)(ws + 4 * MB8);
    unsigned short* kb  = (unsigned short*)(ws + 5 * MB8);
    unsigned short* vb  = (unsigned short*)(ws + 6 * MB8);
    unsigned short* u1t = (unsigned short*)(ws + 3 * MB8);   // 32 MB (cv/qb/kb/vb dead)
    unsigned short* u2t = (unsigned short*)(ws + 7 * MB8);   // 32 MB (weights dead by then)
    // bf16 weights in the [7..10] region; all dead before dwsq writes u2t
    unsigned short* Wq16 = (unsigned short*)(ws + 7 * MB8 + 0 * MB1);
    unsigned short* Wk16 = (unsigned short*)(ws + 7 * MB8 + 2 * MB1);
    unsigned short* Wv16 = (unsigned short*)(ws + 7 * MB8 + 4 * MB1);
    unsigned short* Wo16 = (unsigned short*)(ws + 7 * MB8 + 6 * MB1);
    unsigned short* W116 = (unsigned short*)(ws + 7 * MB8 + 8 * MB1);   // 8 MB
    unsigned short* Awb  = (unsigned short*)(ws + 7 * MB8 + 16 * MB1);  // 15 KB
    unsigned short* W216 = (unsigned short*)(ws + 0 * MB8);  // 8 MB; written after abT dies
    unsigned short* abT = n1;
    unsigned short* pwb = cq;
    unsigned short* n2t = ck;

    ln_kernel<<<dim3(BC, 2), 256, 0, stream>>>(x, g1, b1, n1);
    wrepack<<<dim3(30), 256, 0, stream>>>(conv_q, conv_k, conv_v, Awb);
    cvt5<<<dim3(4096), 256, 0, stream>>>(wq, wk, wv, wo_pw, w1_pw,
                                         Wq16, Wk16, Wv16, Wo16, W116);
    conv3_mfma<<<dim3(8, 64, BB), 256, 0, stream>>>(n1, Awb, cq, ck, cv);
    mgemm3<256, 256, 1, 0><<<dim3(BC, 4, 4), 256, 0, stream>>>(Wq16, cq, qb, nullptr);
    mgemm3<256, 256, 1, 0><<<dim3(BC, 4, 4), 256, 0, stream>>>(Wk16, ck, kb, nullptr);
    mgemm3<256, 256, 1, 0><<<dim3(BC, 4, 4), 256, 0, stream>>>(Wv16, cv, vb, nullptr);
    attn_fused<<<dim3(BC * HH, 8), 256, 0, stream>>>(qb, kb, vb, qkout, abT);
    mgemm3<256, 256, 0, 0><<<dim3(BC, 4, 4), 256, 0, stream>>>(Wo16, abT, pwb, nullptr);
    cvt_bf16<<<dim3(2048), 256, 0, stream>>>(w2_pw, W216, 524288);   // abT now dead
    dwmix<131072, 0><<<dim3(128, BB), 256, 0, stream>>>(pwb, wo_dw, x, hout, nullptr);
    ln_t_kernel<<<dim3(BC, 2), 256, 0, stream>>>(hout, g2, b2, n2t);
    mgemm2<256, 1024, 0, 2><<<dim3(BC, 8, 4), 256, 0, stream>>>(W116, n2t, u1t, nullptr);
    dwmix<524288, 1><<<dim3(512, BB), 256, 0, stream>>>(u1t, w1_dw, nullptr, nullptr, u2t);
    mgemm3<1024, 256, 0, 1><<<dim3(BC, 4, 4), 256, 0, stream>>>(W216, u2t, nullptr, hout);
}

// Round 8
// 287.324 us; speedup vs baseline: 1.3115x; 1.1746x over previous
//
#include <hip/hip_runtime.h>

#define BB 2
#define CC 16
#define BC 32
#define FF 256
#define WW 512
#define HH 8
#define DH 32

using bf16x8 = __attribute__((ext_vector_type(8))) __bf16;
using f32x4  = __attribute__((ext_vector_type(4))) float;
using us8    = __attribute__((ext_vector_type(8))) unsigned short;
using us4    = __attribute__((ext_vector_type(4))) unsigned short;

__device__ __forceinline__ float bf2f(unsigned short u) {
    union { unsigned int i; float f; } x; x.i = ((unsigned int)u) << 16; return x.f;
}
__device__ __forceinline__ unsigned short f2bf(float f) {
    union { float f; unsigned int i; } x; x.f = f;
    unsigned int r = x.i + 0x7fffu + ((x.i >> 16) & 1u);   // round-nearest-even
    return (unsigned short)(r >> 16);
}
__device__ __forceinline__ f32x4 mfma16(bf16x8 a, bf16x8 b, f32x4 c) {
    return __builtin_amdgcn_mfma_f32_16x16x32_bf16(a, b, c, 0, 0, 0);
}

// ---------------- prep: all weight cvts + conv wrepack in one launch ----------------
__global__ __launch_bounds__(256) void prep(
    const float* __restrict__ wq, const float* __restrict__ wk,
    const float* __restrict__ wv, const float* __restrict__ wo,
    const float* __restrict__ w1, const float* __restrict__ w2,
    const float* __restrict__ cwq, const float* __restrict__ cwk,
    const float* __restrict__ cwv,
    unsigned short* __restrict__ Wqkv, unsigned short* __restrict__ Wo16,
    unsigned short* __restrict__ W116, unsigned short* __restrict__ W216,
    unsigned short* __restrict__ Aw) {
    int bid = blockIdx.x;
    if (bid < 6144) {
        int i = bid * 256 + threadIdx.x;
        const float* s; unsigned short* d; int off;
        if (i < 131072)       { s = wq; d = Wqkv;            off = i; }
        else if (i < 262144)  { s = wk; d = Wqkv + 1048576;  off = i - 131072; }
        else if (i < 393216)  { s = wv; d = Wqkv + 2097152;  off = i - 262144; }
        else if (i < 524288)  { s = wo; d = Wo16;            off = i - 393216; }
        else if (i < 1048576) { s = w1; d = W116;            off = i - 524288; }
        else                  { s = w2; d = W216;            off = i - 1048576; }
        const float4* sp = (const float4*)s + (size_t)off * 2;
        float4 a = sp[0], b = sp[1];
        us8 p;
        p[0] = f2bf(a.x); p[1] = f2bf(a.y); p[2] = f2bf(a.z); p[3] = f2bf(a.w);
        p[4] = f2bf(b.x); p[5] = f2bf(b.y); p[6] = f2bf(b.z); p[7] = f2bf(b.w);
        *((us8*)d + off) = p;
    } else {
        int idx = (bid - 6144) * 256 + threadIdx.x;
        if (idx < 7680) {
            int tensor = idx / 2560;
            int r = idx - tensor * 2560;
            int tp = r >> 9, co = (r >> 5) & 15, k = r & 31;
            int tap = tp * 2 + (k >> 4), ci = k & 15;
            float v = 0.f;
            if (tap < 9) {
                const float* w = tensor == 0 ? cwq : (tensor == 1 ? cwk : cwv);
                v = w[(co * 16 + ci) * 9 + tap];
            }
            Aw[idx] = f2bf(v);
        }
    }
}

// ---------------- LayerNorm, 4-way f-split. TR=0: [f][w]; TR=1: [w][f] ----------------
template <int TR>
__global__ __launch_bounds__(256) void ln2_kernel(
    const float* __restrict__ x, const float* __restrict__ g,
    const float* __restrict__ bta, unsigned short* __restrict__ out) {
    __shared__ float red[2][4][64];
    __shared__ float mr[2][64];
    int bc = blockIdx.x, c = bc & 15;
    int part = threadIdx.x >> 6, wl = threadIdx.x & 63;
    int w = blockIdx.y * 64 + wl;
    const float* xp = x + ((size_t)bc * FF + part * 64) * WW + w;
    float s = 0.f, s2 = 0.f;
#pragma unroll 4
    for (int i = 0; i < 64; ++i) { float t = xp[(size_t)i * WW]; s += t; s2 += t * t; }
    red[0][part][wl] = s; red[1][part][wl] = s2;
    __syncthreads();
    if (part == 0) {
        float S  = red[0][0][wl] + red[0][1][wl] + red[0][2][wl] + red[0][3][wl];
        float S2 = red[1][0][wl] + red[1][1][wl] + red[1][2][wl] + red[1][3][wl];
        float m = S * (1.f / FF);
        float v = S2 * (1.f / FF) - m * m;
        mr[0][wl] = m; mr[1][wl] = rsqrtf(v + 1e-5f);
    }
    __syncthreads();
    float m = mr[0][wl], r = mr[1][wl];
    const float* gp = g + c * FF + part * 64;
    const float* bp = bta + c * FF + part * 64;
    if (TR == 0) {
        unsigned short* op = out + ((size_t)bc * FF + part * 64) * WW + w;
#pragma unroll 4
        for (int i = 0; i < 64; ++i)
            op[(size_t)i * WW] = f2bf((xp[(size_t)i * WW] - m) * r * gp[i] + bp[i]);
    } else {
        unsigned short* op = out + ((size_t)bc * WW + w) * FF + part * 64;
        for (int i8 = 0; i8 < 8; ++i8) {
            us8 pk;
#pragma unroll
            for (int e = 0; e < 8; ++e) {
                int i = i8 * 8 + e;
                pk[e] = f2bf((xp[(size_t)i * WW] - m) * r * gp[i] + bp[i]);
            }
            *(us8*)(op + i8 * 8) = pk;
        }
    }
}

// ---------------- MFMA conv3x3 (unchanged) ----------------
__global__ __launch_bounds__(256) void conv3_mfma(
    const unsigned short* __restrict__ n1, const unsigned short* __restrict__ Aw,
    unsigned short* __restrict__ oq, unsigned short* __restrict__ ok,
    unsigned short* __restrict__ ov) {
    __shared__ __align__(16) unsigned short Xl[6][68][16];
    const int b = blockIdx.z;
    const int f0 = blockIdx.y * 4;
    const int w0 = blockIdx.x * 64;
    const int tx = threadIdx.x;
    const int lane = tx & 63, wid = tx >> 6;
    const int lr = lane & 15, lg = lane >> 4;
    {
        uint4 z{0, 0, 0, 0};
        for (int i = tx; i < 816; i += 256) ((uint4*)Xl)[i] = z;
    }
    __syncthreads();
    for (int task = tx; task < 960; task += 256) {
        int c = task % 10;
        int fr = (task / 10) % 6;
        int ci = task / 60;
        int fy = f0 - 1 + fr;
        int wx = w0 - 8 + c * 8;
        if (fy >= 0 && fy < FF && wx >= 0 && wx <= WW - 8) {
            us8 v = *(const us8*)(n1 + ((size_t)(b * CC + ci) * FF + fy) * WW + wx);
#pragma unroll
            for (int e = 0; e < 8; ++e) {
                int wl = c * 8 + e - 7;
                if (wl >= 0 && wl < 66) Xl[fr][wl][ci] = v[e];
            }
        }
    }
    __syncthreads();
    bf16x8 A[3][5];
#pragma unroll
    for (int t3 = 0; t3 < 3; ++t3)
#pragma unroll
        for (int t = 0; t < 5; ++t)
            A[t3][t] = *(const bf16x8*)(Aw + ((t3 * 5 + t) * 16 + lr) * 32 + lg * 8);
    const bool h = (lane & 32) != 0;
    int doff[5];
    doff[0] = (h ? (-68 * 32) : ((-68 - 1) * 32));
    doff[1] = (h ? (-1 * 32) : ((-68 + 1) * 32));
    doff[2] = (h ? (1 * 32) : 0);
    doff[3] = (h ? (68 * 32) : ((68 - 1) * 32));
    doff[4] = ((68 + 1) * 32);
    const int fl = wid + 1;
    const int fglob = f0 + wid;
    char* xbase = (char*)Xl + (fl * 68 + 1) * 32 + ((lg & 1) ? 16 : 0);
#pragma unroll
    for (int pt = 0; pt < 4; ++pt) {
        char* bb = xbase + (pt * 16 + lr) * 32;
        bf16x8 Bf[5];
#pragma unroll
        for (int t = 0; t < 5; ++t) Bf[t] = *(const bf16x8*)(bb + doff[t]);
        f32x4 aq = {0.f, 0.f, 0.f, 0.f}, ak = {0.f, 0.f, 0.f, 0.f}, av = {0.f, 0.f, 0.f, 0.f};
#pragma unroll
        for (int t = 0; t < 5; ++t) {
            aq = mfma16(A[0][t], Bf[t], aq);
            ak = mfma16(A[1][t], Bf[t], ak);
            av = mfma16(A[2][t], Bf[t], av);
        }
        int w = w0 + pt * 16 + lr;
#pragma unroll
        for (int r = 0; r < 4; ++r) {
            int co = lg * 4 + r;
            size_t o = ((size_t)(b * CC + co) * FF + fglob) * WW + w;
            oq[o] = f2bf(aq[r]);
            ok[o] = f2bf(ak[r]);
            ov[o] = f2bf(av[r]);
        }
    }
}

// ---------------- 64x128-tile MFMA GEMM, XCD-swizzled 1D grid ----------------
// grid = NT*BC*4(z)*4(g); id: low3=xcd key, g bits 3-4, rest = group.
// B-panel-sharing blocks (same t,bc,z; 4 g) have equal id%8 -> same XCD L2.
template <int K, int BSRC, int MODE, int NT>
__global__ __launch_bounds__(256, 3) void mgemm3(
    const unsigned short* __restrict__ Wb, const unsigned short* __restrict__ T,
    unsigned short* __restrict__ ob, float* __restrict__ of) {
    constexpr int M = 256;
    __shared__ __align__(16) unsigned short Al[64 * 64];
    __shared__ __align__(16) unsigned short Bl[128 * 64];
    const int id = blockIdx.x;
    const int grp = ((id >> 5) << 3) | (id & 7);
    const int g = (id >> 3) & 3;
    const int t = (NT > 1) ? (grp >> 7) : 0;
    const int rem = grp & 127;
    const int bc = rem >> 2, z = rem & 3;
    const int c = bc & 15;
    const int G0 = g * 64, W0 = z * 128;
    const int tx = threadIdx.x;
    const int lane = tx & 63, wid = tx >> 6;
    const int lr = lane & 15, lg = lane >> 4;
    const int wr = wid >> 1, wc = wid & 1;
    const unsigned short* Ab = Wb + (size_t)t * 1048576 + ((size_t)c * M + G0) * K;
    const unsigned short* Tt = T + (size_t)t * 4194304;
    f32x4 acc[2][4];
#pragma unroll
    for (int i = 0; i < 2; ++i)
#pragma unroll
        for (int j = 0; j < 4; ++j) acc[i][j] = (f32x4){0.f, 0.f, 0.f, 0.f};

    for (int f0 = 0; f0 < K; f0 += 64) {
#pragma unroll
        for (int rep = 0; rep < 2; ++rep) {
            int idx = tx + rep * 256;
            int row = idx >> 3, seg = idx & 7;
            us8 v = *(const us8*)(Ab + (size_t)row * K + f0 + seg * 8);
            *(us8*)((char*)Al + row * 128 + ((seg ^ (row & 7)) << 4)) = v;
        }
        if (BSRC == 0) {
            const unsigned short* Tb = Tt + ((size_t)bc * WW + W0) * K;
#pragma unroll
            for (int rep = 0; rep < 4; ++rep) {
                int idx = tx + rep * 256;
                int row = idx >> 3, seg = idx & 7;
                us8 v = *(const us8*)(Tb + (size_t)row * K + f0 + seg * 8);
                *(us8*)((char*)Bl + row * 128 +
                        ((seg ^ (row & 7) ^ ((row >> 3) & 7)) << 4)) = v;
            }
        } else {
            const unsigned short* Tb = Tt + (size_t)bc * K * WW;
            const int wseg = tx & 15, fgrp = tx >> 4;
            us8 tv[4];
#pragma unroll
            for (int i = 0; i < 4; ++i)
                tv[i] = *(const us8*)(Tb + (size_t)(f0 + fgrp * 4 + i) * WW + W0 + wseg * 8);
#pragma unroll
            for (int j = 0; j < 8; ++j) {
                int w = wseg * 8 + j;
                us4 p; p.x = tv[0][j]; p.y = tv[1][j]; p.z = tv[2][j]; p.w = tv[3][j];
                *(us4*)((char*)Bl + w * 128 +
                        ((((fgrp >> 1) ^ (w & 7) ^ ((w >> 3) & 7)) << 4)) + (fgrp & 1) * 8) = p;
            }
        }
        __syncthreads();
#pragma unroll
        for (int kc = 0; kc < 2; ++kc) {
            bf16x8 af[2], bf[4];
#pragma unroll
            for (int i = 0; i < 2; ++i) {
                int gr = wr * 32 + i * 16 + lr;
                af[i] = *(const bf16x8*)((char*)Al + gr * 128 +
                        (((kc * 4 + lg) ^ (gr & 7)) << 4));
            }
#pragma unroll
            for (int j = 0; j < 4; ++j) {
                int wrw = wc * 64 + j * 16 + lr;
                bf[j] = *(const bf16x8*)((char*)Bl + wrw * 128 +
                        (((kc * 4 + lg) ^ (wrw & 7) ^ ((wrw >> 3) & 7)) << 4));
            }
#pragma unroll
            for (int i = 0; i < 2; ++i)
#pragma unroll
                for (int j = 0; j < 4; ++j)
                    acc[i][j] = mfma16(af[i], bf[j], acc[i][j]);
        }
        __syncthreads();
    }
#pragma unroll
    for (int i = 0; i < 2; ++i)
#pragma unroll
        for (int j = 0; j < 4; ++j) {
            int g2 = G0 + wr * 32 + i * 16 + lg * 4;
            int w = W0 + wc * 64 + j * 16 + lr;
#pragma unroll
            for (int r = 0; r < 4; ++r) {
                size_t o = (size_t)t * 4194304 + ((size_t)bc * M + g2 + r) * WW + w;
                if (MODE == 0) ob[o] = f2bf(acc[i][j][r]);
                else of[o] += acc[i][j][r];
            }
        }
}

// ---------------- 128x128-tile MFMA GEMM (FFN-up, M=1024), XCD-swizzled ----------------
template <int K, int M, int MODE>
__global__ __launch_bounds__(256, 2) void mgemm2(
    const unsigned short* __restrict__ Wb, const unsigned short* __restrict__ T,
    unsigned short* __restrict__ ob, float* __restrict__ of) {
    __shared__ __align__(16) unsigned short Al[128 * 64];
    __shared__ __align__(16) unsigned short Bl[128 * 64];
    const int id = blockIdx.x;
    const int grp = ((id >> 6) << 3) | (id & 7);
    const int g = (id >> 3) & 7;
    const int bc = grp >> 2, z = grp & 3;
    const int c = bc & 15;
    const int G0 = g * 128, W0 = z * 128;
    const int tx = threadIdx.x;
    const int lane = tx & 63, wid = tx >> 6;
    const int lr = lane & 15, lg = lane >> 4;
    const int wr = wid >> 1, wc = wid & 1;
    const unsigned short* Ab = Wb + ((size_t)c * M + G0) * K;
    f32x4 acc[4][4];
#pragma unroll
    for (int i = 0; i < 4; ++i)
#pragma unroll
        for (int j = 0; j < 4; ++j) acc[i][j] = (f32x4){0.f, 0.f, 0.f, 0.f};

    for (int f0 = 0; f0 < K; f0 += 64) {
#pragma unroll
        for (int rep = 0; rep < 4; ++rep) {
            int idx = tx + rep * 256;
            int row = idx >> 3, seg = idx & 7;
            us8 v = *(const us8*)(Ab + (size_t)row * K + f0 + seg * 8);
            *(us8*)((char*)Al + row * 128 + ((seg ^ (row & 7)) << 4)) = v;
        }
        {
            const unsigned short* Tb = T + ((size_t)bc * WW + W0) * K;
#pragma unroll
            for (int rep = 0; rep < 4; ++rep) {
                int idx = tx + rep * 256;
                int row = idx >> 3, seg = idx & 7;
                us8 v = *(const us8*)(Tb + (size_t)row * K + f0 + seg * 8);
                *(us8*)((char*)Bl + row * 128 +
                        ((seg ^ (row & 7) ^ ((row >> 3) & 7)) << 4)) = v;
            }
        }
        __syncthreads();
#pragma unroll
        for (int kc = 0; kc < 2; ++kc) {
            bf16x8 af[4], bf[4];
#pragma unroll
            for (int i = 0; i < 4; ++i) {
                int gr = wr * 64 + i * 16 + lr;
                af[i] = *(const bf16x8*)((char*)Al + gr * 128 +
                        (((kc * 4 + lg) ^ (gr & 7)) << 4));
                int wrw = wc * 64 + i * 16 + lr;
                bf[i] = *(const bf16x8*)((char*)Bl + wrw * 128 +
                        (((kc * 4 + lg) ^ (wrw & 7) ^ ((wrw >> 3) & 7)) << 4));
            }
#pragma unroll
            for (int i = 0; i < 4; ++i)
#pragma unroll
                for (int j = 0; j < 4; ++j)
                    acc[i][j] = mfma16(af[i], bf[j], acc[i][j]);
        }
        __syncthreads();
    }
#pragma unroll
    for (int i = 0; i < 4; ++i)
#pragma unroll
        for (int j = 0; j < 4; ++j) {
            int gg = G0 + wr * 64 + i * 16 + lg * 4;
            int w = W0 + wc * 64 + j * 16 + lr;
            if (MODE == 2) {
                us4 pk;
                pk.x = f2bf(acc[i][j][0]); pk.y = f2bf(acc[i][j][1]);
                pk.z = f2bf(acc[i][j][2]); pk.w = f2bf(acc[i][j][3]);
                *(us4*)(ob + ((size_t)bc * WW + w) * M + gg) = pk;
            } else {
#pragma unroll
                for (int r = 0; r < 4; ++r) {
                    size_t o = ((size_t)bc * M + gg + r) * WW + w;
                    if (MODE == 0) ob[o] = f2bf(acc[i][j][r]);
                    else of[o] += acc[i][j][r];
                }
            }
        }
}

// ---------------- fused attention v3 (unchanged) ----------------
__global__ __launch_bounds__(256, 2) void attn_fused(
    const unsigned short* __restrict__ qb, const unsigned short* __restrict__ kb,
    const unsigned short* __restrict__ vb, float* __restrict__ qko,
    unsigned short* __restrict__ abT) {
    __shared__ unsigned short Kl[512 * 32];
    __shared__ unsigned short Vl[32 * 512];
    __shared__ unsigned short Ql[64 * 32];
    const int bch = blockIdx.x, qt = blockIdx.y;
    const int bc = bch >> 3, h = bch & 7;
    const int tx = threadIdx.x;
    const int lane = tx & 63, wid = tx >> 6;
    const int lr = lane & 15, lg = lane >> 4;

    const unsigned short* kbase = kb + ((size_t)bc * FF + h * DH) * WW;
    const unsigned short* vbase = vb + ((size_t)bc * FF + h * DH) * WW;
    const unsigned short* qbase = qb + ((size_t)bc * FF + h * DH) * WW + qt * 64;

    {
        int d0 = ((tx >> 3) & 7) * 4;
#pragma unroll
        for (int rep = 0; rep < 2; ++rep) {
            int kw0 = (tx & 7) * 8 + ((tx >> 6) & 3) * 64 + rep * 256;
            us8 v0 = *(const us8*)(kbase + (size_t)(d0 + 0) * WW + kw0);
            us8 v1 = *(const us8*)(kbase + (size_t)(d0 + 1) * WW + kw0);
            us8 v2 = *(const us8*)(kbase + (size_t)(d0 + 2) * WW + kw0);
            us8 v3 = *(const us8*)(kbase + (size_t)(d0 + 3) * WW + kw0);
#pragma unroll
            for (int j = 0; j < 8; ++j) {
                int kw = kw0 + j;
                us4 p; p.x = v0[j]; p.y = v1[j]; p.z = v2[j]; p.w = v3[j];
                *(us4*)((char*)Kl + kw * 64 + ((d0 * 2) ^ ((kw & 3) << 4))) = p;
            }
        }
    }
    {
        int d = tx >> 3;
        int sw = (d & 7) << 4;
#pragma unroll
        for (int rep = 0; rep < 8; ++rep) {
            int kw0 = (tx & 7) * 8 + rep * 64;
            us8 tv = *(const us8*)(vbase + (size_t)d * WW + kw0);
            *(us8*)((char*)Vl + d * 1024 + ((kw0 * 2) ^ sw)) = tv;
        }
    }
    if (tx < 64) {
        int d0 = ((tx >> 3) & 7) * 4;
        int q0 = (tx & 7) * 8;
        us8 v0 = *(const us8*)(qbase + (size_t)(d0 + 0) * WW + q0);
        us8 v1 = *(const us8*)(qbase + (size_t)(d0 + 1) * WW + q0);
        us8 v2 = *(const us8*)(qbase + (size_t)(d0 + 2) * WW + q0);
        us8 v3 = *(const us8*)(qbase + (size_t)(d0 + 3) * WW + q0);
#pragma unroll
        for (int j = 0; j < 8; ++j) {
            us4 p; p.x = v0[j]; p.y = v1[j]; p.z = v2[j]; p.w = v3[j];
            *(us4*)(&Ql[(q0 + j) * 32 + d0]) = p;
        }
    }
    __syncthreads();

    const int q0w = wid * 16;
    bf16x8 qf = *(const bf16x8*)((char*)Ql + (q0w + lr) * 64 + lg * 16);
    f32x4 s[32];
#pragma unroll
    for (int i = 0; i < 32; ++i) s[i] = (f32x4){0.f, 0.f, 0.f, 0.f};
#pragma unroll
    for (int kwt = 0; kwt < 32; ++kwt) {
        int krow = kwt * 16 + lr;
        bf16x8 kf = *(const bf16x8*)((char*)Kl + krow * 64 + ((lg * 16) ^ ((krow & 3) << 4)));
        s[kwt] = mfma16(kf, qf, s[kwt]);
    }
    float mx = -3.0e38f;
    float* qrow = qko + ((size_t)bch * WW + qt * 64 + q0w + lr) * WW;
#pragma unroll
    for (int kwt = 0; kwt < 32; ++kwt) {
        s[kwt] *= 0.0625f;
        float4 st;
        st.x = s[kwt][0]; st.y = s[kwt][1]; st.z = s[kwt][2]; st.w = s[kwt][3];
        *(float4*)(qrow + kwt * 16 + lg * 4) = st;
        mx = fmaxf(mx, fmaxf(fmaxf(st.x, st.y), fmaxf(st.z, st.w)));
    }
    mx = fmaxf(mx, __shfl_xor(mx, 16));
    mx = fmaxf(mx, __shfl_xor(mx, 32));
    float sum = 0.f;
#pragma unroll
    for (int kwt = 0; kwt < 32; ++kwt) {
#pragma unroll
        for (int r = 0; r < 4; ++r) {
            float p = __expf(s[kwt][r] - mx);
            s[kwt][r] = p;
            sum += p;
        }
    }
    sum += __shfl_xor(sum, 16);
    sum += __shfl_xor(sum, 32);
    float inv = 1.0f / sum;

    f32x4 av[2];
    av[0] = (f32x4){0.f, 0.f, 0.f, 0.f};
    av[1] = (f32x4){0.f, 0.f, 0.f, 0.f};
#pragma unroll
    for (int t = 0; t < 16; ++t) {
        unsigned pa0 = f2bf(s[2 * t][0]) | ((unsigned)f2bf(s[2 * t][1]) << 16);
        unsigned pa1 = f2bf(s[2 * t][2]) | ((unsigned)f2bf(s[2 * t][3]) << 16);
        unsigned pb0 = f2bf(s[2 * t + 1][0]) | ((unsigned)f2bf(s[2 * t + 1][1]) << 16);
        unsigned pb1 = f2bf(s[2 * t + 1][2]) | ((unsigned)f2bf(s[2 * t + 1][3]) << 16);
        unsigned s16_0 = (lg == 1) ? pa0 : pb0, s16_1 = (lg == 1) ? pa1 : pb1;
        unsigned s32_0 = (lg == 3) ? pa0 : pb0, s32_1 = (lg == 3) ? pa1 : pb1;
        unsigned s48_0 = (lg == 2) ? pa0 : pb0, s48_1 = (lg == 2) ? pa1 : pb1;
        unsigned r16_0 = (unsigned)__shfl_xor((int)s16_0, 16);
        unsigned r16_1 = (unsigned)__shfl_xor((int)s16_1, 16);
        unsigned r32_0 = (unsigned)__shfl_xor((int)s32_0, 32);
        unsigned r32_1 = (unsigned)__shfl_xor((int)s32_1, 32);
        unsigned r48_0 = (unsigned)__shfl_xor((int)s48_0, 48);
        unsigned r48_1 = (unsigned)__shfl_xor((int)s48_1, 48);
        uint4 wv;
        if (lg == 0)      { wv.x = pa0;   wv.y = pa1;   wv.z = r16_0; wv.w = r16_1; }
        else if (lg == 1) { wv.x = r48_0; wv.y = r48_1; wv.z = r32_0; wv.w = r32_1; }
        else if (lg == 2) { wv.x = r32_0; wv.y = r32_1; wv.z = r48_0; wv.w = r48_1; }
        else              { wv.x = r16_0; wv.y = r16_1; wv.z = pb0;  wv.w = pb1; }
        bf16x8 pf = *reinterpret_cast<bf16x8*>(&wv);
#pragma unroll
        for (int di = 0; di < 2; ++di) {
            int vr = di * 16 + lr;
            bf16x8 vf = *(const bf16x8*)((char*)Vl + vr * 1024 + ((t * 64 + lg * 16) ^ ((vr & 7) << 4)));
            av[di] = mfma16(vf, pf, av[di]);
        }
    }
    unsigned short* arow = abT + ((size_t)bc * WW + qt * 64 + q0w + lr) * FF + h * DH;
#pragma unroll
    for (int di = 0; di < 2; ++di) {
        us4 pk;
        pk.x = f2bf(av[di][0] * inv); pk.y = f2bf(av[di][1] * inv);
        pk.z = f2bf(av[di][2] * inv); pk.w = f2bf(av[di][3] * inv);
        *(us4*)(arow + di * 16 + lg * 4) = pk;
    }
}

// ---------------- LDS-tiled depthwise 16-ch mix ----------------
template <int NPC, int MODE>
__global__ __launch_bounds__(256) void dwmix(
    const unsigned short* __restrict__ in, const float* __restrict__ wdw,
    const float* __restrict__ x, float* __restrict__ fo, unsigned short* __restrict__ bo) {
    __shared__ unsigned short L[16][1024];
    int b = blockIdx.y;
    size_t base = (size_t)blockIdx.x * 1024;
    int tx = threadIdx.x;
#pragma unroll
    for (int r = 0; r < 8; ++r) {
        int idx = tx + r * 256;
        int ci = idx >> 7;
        int seg = idx & 127;
        *(us8*)&L[ci][seg * 8] = *(const us8*)(in + ((size_t)(b * 16 + ci)) * NPC + base + seg * 8);
    }
    __syncthreads();
#pragma unroll
    for (int pos = 0; pos < 4; ++pos) {
        int fw = tx + pos * 256;
        float vin[16];
#pragma unroll
        for (int ci = 0; ci < 16; ++ci) vin[ci] = bf2f(L[ci][fw]);
#pragma unroll
        for (int o = 0; o < 16; ++o) {
            float s = 0.f;
#pragma unroll
            for (int ci = 0; ci < 16; ++ci) s += wdw[o * 16 + ci] * vin[ci];
            size_t oi = ((size_t)(b * 16 + o)) * NPC + base + fw;
            if (MODE == 0) fo[oi] = x[oi] + s;
            else { s = fmaxf(s, 0.f); bo[oi] = f2bf(s * s); }
        }
    }
}

extern "C" void kernel_launch(void* const* d_in, const int* in_sizes, int n_in,
                              void* d_out, int out_size, void* d_ws, size_t ws_size,
                              hipStream_t stream) {
    const float* x      = (const float*)d_in[0];
    const float* conv_q = (const float*)d_in[1];
    const float* conv_k = (const float*)d_in[2];
    const float* conv_v = (const float*)d_in[3];
    const float* wq     = (const float*)d_in[4];
    const float* wk     = (const float*)d_in[5];
    const float* wv     = (const float*)d_in[6];
    const float* wo_pw  = (const float*)d_in[7];
    const float* wo_dw  = (const float*)d_in[8];
    const float* g1     = (const float*)d_in[9];
    const float* b1     = (const float*)d_in[10];
    const float* g2     = (const float*)d_in[11];
    const float* b2     = (const float*)d_in[12];
    const float* w1_pw  = (const float*)d_in[13];
    const float* w1_dw  = (const float*)d_in[14];
    const float* w2_pw  = (const float*)d_in[15];

    float* hout  = (float*)d_out;
    float* qkout = (float*)d_out + 4194304;

    char* ws = (char*)d_ws;
    const size_t MB1 = (size_t)1 << 20;
    unsigned short* n1   = (unsigned short*)(ws + 0 * MB1);
    unsigned short* cq   = (unsigned short*)(ws + 8 * MB1);    // cq/ck/cv contiguous (4M-elem stride)
    unsigned short* qb   = (unsigned short*)(ws + 32 * MB1);   // qb/kb/vb contiguous
    unsigned short* kb   = (unsigned short*)(ws + 40 * MB1);
    unsigned short* vb   = (unsigned short*)(ws + 48 * MB1);
    unsigned short* abT  = (unsigned short*)(ws + 56 * MB1);
    unsigned short* pwb  = (unsigned short*)(ws + 64 * MB1);
    unsigned short* n2t  = (unsigned short*)(ws + 72 * MB1);
    unsigned short* u1t  = (unsigned short*)(ws + 80 * MB1);   // 32 MB
    unsigned short* u2t  = (unsigned short*)(ws + 112 * MB1);  // 32 MB
    unsigned short* Wqkv = (unsigned short*)(ws + 144 * MB1);  // 6 MB (3 x 1M elems)
    unsigned short* Wo16 = (unsigned short*)(ws + 150 * MB1);  // 2 MB
    unsigned short* W116 = (unsigned short*)(ws + 152 * MB1);  // 8 MB
    unsigned short* W216 = (unsigned short*)(ws + 160 * MB1);  // 8 MB
    unsigned short* Awb  = (unsigned short*)(ws + 168 * MB1);  // 15 KB

    prep<<<dim3(6174), 256, 0, stream>>>(wq, wk, wv, wo_pw, w1_pw, w2_pw,
                                         conv_q, conv_k, conv_v,
                                         Wqkv, Wo16, W116, W216, Awb);
    ln2_kernel<0><<<dim3(BC, 8), 256, 0, stream>>>(x, g1, b1, n1);
    conv3_mfma<<<dim3(8, 64, BB), 256, 0, stream>>>(n1, Awb, cq, cq + 4194304, cq + 8388608);
    mgemm3<256, 1, 0, 3><<<dim3(1536), 256, 0, stream>>>(Wqkv, cq, qb, nullptr);
    attn_fused<<<dim3(BC * HH, 8), 256, 0, stream>>>(qb, kb, vb, qkout, abT);
    mgemm3<256, 0, 0, 1><<<dim3(512), 256, 0, stream>>>(Wo16, abT, pwb, nullptr);
    dwmix<131072, 0><<<dim3(128, BB), 256, 0, stream>>>(pwb, wo_dw, x, hout, nullptr);
    ln2_kernel<1><<<dim3(BC, 8), 256, 0, stream>>>(hout, g2, b2, n2t);
    mgemm2<256, 1024, 2><<<dim3(1024), 256, 0, stream>>>(W116, n2t, u1t, nullptr);
    dwmix<524288, 1><<<dim3(512, BB), 256, 0, stream>>>(u1t, w1_dw, nullptr, nullptr, u2t);
    mgemm3<1024, 0, 1, 1><<<dim3(512), 256, 0, stream>>>(W216, u2t, nullptr, hout);
}

// Round 9
// 281.255 us; speedup vs baseline: 1.3398x; 1.0216x over previous
//
#include <hip/hip_runtime.h>

#define BB 2
#define CC 16
#define BC 32
#define FF 256
#define WW 512
#define HH 8
#define DH 32

using bf16x8 = __attribute__((ext_vector_type(8))) __bf16;
using f32x4  = __attribute__((ext_vector_type(4))) float;
using us8    = __attribute__((ext_vector_type(8))) unsigned short;
using us4    = __attribute__((ext_vector_type(4))) unsigned short;

#define AS1 __attribute__((address_space(1)))
#define AS3 __attribute__((address_space(3)))

__device__ __forceinline__ float bf2f(unsigned short u) {
    union { unsigned int i; float f; } x; x.i = ((unsigned int)u) << 16; return x.f;
}
__device__ __forceinline__ unsigned short f2bf(float f) {
    union { float f; unsigned int i; } x; x.f = f;
    unsigned int r = x.i + 0x7fffu + ((x.i >> 16) & 1u);   // round-nearest-even
    return (unsigned short)(r >> 16);
}
__device__ __forceinline__ f32x4 mfma16(bf16x8 a, bf16x8 b, f32x4 c) {
    return __builtin_amdgcn_mfma_f32_16x16x32_bf16(a, b, c, 0, 0, 0);
}
// async global->LDS, 16B per lane; lds dest = wave-uniform base + lane*16
__device__ __forceinline__ void gload16(const void* g, void* l) {
    __builtin_amdgcn_global_load_lds((AS1 void*)g, (AS3 void*)l, 16, 0, 0);
}

// ---------------- prep (weight cvt + conv repack) fused with LayerNorm1 ----------------
__global__ __launch_bounds__(256) void prep_ln(
    const float* __restrict__ x, const float* __restrict__ g1,
    const float* __restrict__ b1, unsigned short* __restrict__ n1,
    const float* __restrict__ wq, const float* __restrict__ wk,
    const float* __restrict__ wv, const float* __restrict__ wo,
    const float* __restrict__ w1, const float* __restrict__ w2,
    const float* __restrict__ cwq, const float* __restrict__ cwk,
    const float* __restrict__ cwv,
    unsigned short* __restrict__ Wqkv, unsigned short* __restrict__ Wo16,
    unsigned short* __restrict__ W116, unsigned short* __restrict__ W216,
    unsigned short* __restrict__ Aw) {
    __shared__ float red[2][4][64];
    __shared__ float mr[2][64];
    int bid = blockIdx.x;
    if (bid < 256) {
        // LayerNorm over f -> [f][w] bf16
        int bc = bid & 31, c = bc & 15;
        int part = threadIdx.x >> 6, wl = threadIdx.x & 63;
        int w = (bid >> 5) * 64 + wl;
        const float* xp = x + ((size_t)bc * FF + part * 64) * WW + w;
        float s = 0.f, s2 = 0.f;
#pragma unroll 4
        for (int i = 0; i < 64; ++i) { float t = xp[(size_t)i * WW]; s += t; s2 += t * t; }
        red[0][part][wl] = s; red[1][part][wl] = s2;
        __syncthreads();
        if (part == 0) {
            float S  = red[0][0][wl] + red[0][1][wl] + red[0][2][wl] + red[0][3][wl];
            float S2 = red[1][0][wl] + red[1][1][wl] + red[1][2][wl] + red[1][3][wl];
            float m = S * (1.f / FF);
            float v = S2 * (1.f / FF) - m * m;
            mr[0][wl] = m; mr[1][wl] = rsqrtf(v + 1e-5f);
        }
        __syncthreads();
        float m = mr[0][wl], r = mr[1][wl];
        const float* gp = g1 + c * FF + part * 64;
        const float* bp = b1 + c * FF + part * 64;
        unsigned short* op = n1 + ((size_t)bc * FF + part * 64) * WW + w;
#pragma unroll 4
        for (int i = 0; i < 64; ++i)
            op[(size_t)i * WW] = f2bf((xp[(size_t)i * WW] - m) * r * gp[i] + bp[i]);
    } else if (bid < 256 + 6144) {
        int i = (bid - 256) * 256 + threadIdx.x;
        const float* s; unsigned short* d; int off;
        if (i < 131072)       { s = wq; d = Wqkv;            off = i; }
        else if (i < 262144)  { s = wk; d = Wqkv + 1048576;  off = i - 131072; }
        else if (i < 393216)  { s = wv; d = Wqkv + 2097152;  off = i - 262144; }
        else if (i < 524288)  { s = wo; d = Wo16;            off = i - 393216; }
        else if (i < 1048576) { s = w1; d = W116;            off = i - 524288; }
        else                  { s = w2; d = W216;            off = i - 1048576; }
        const float4* sp = (const float4*)s + (size_t)off * 2;
        float4 a = sp[0], b = sp[1];
        us8 p;
        p[0] = f2bf(a.x); p[1] = f2bf(a.y); p[2] = f2bf(a.z); p[3] = f2bf(a.w);
        p[4] = f2bf(b.x); p[5] = f2bf(b.y); p[6] = f2bf(b.z); p[7] = f2bf(b.w);
        *((us8*)d + off) = p;
    } else {
        int idx = (bid - 256 - 6144) * 256 + threadIdx.x;
        if (idx < 7680) {
            int tensor = idx / 2560;
            int r = idx - tensor * 2560;
            int tp = r >> 9, co = (r >> 5) & 15, k = r & 31;
            int tap = tp * 2 + (k >> 4), ci = k & 15;
            float v = 0.f;
            if (tap < 9) {
                const float* w = tensor == 0 ? cwq : (tensor == 1 ? cwk : cwv);
                v = w[(co * 16 + ci) * 9 + tap];
            }
            Aw[idx] = f2bf(v);
        }
    }
}

// ---------------- LayerNorm, 4-way f-split, transposed out [w][f] ----------------
__global__ __launch_bounds__(256) void ln2t_kernel(
    const float* __restrict__ x, const float* __restrict__ g,
    const float* __restrict__ bta, unsigned short* __restrict__ out) {
    __shared__ float red[2][4][64];
    __shared__ float mr[2][64];
    int bc = blockIdx.x, c = bc & 15;
    int part = threadIdx.x >> 6, wl = threadIdx.x & 63;
    int w = blockIdx.y * 64 + wl;
    const float* xp = x + ((size_t)bc * FF + part * 64) * WW + w;
    float s = 0.f, s2 = 0.f;
#pragma unroll 4
    for (int i = 0; i < 64; ++i) { float t = xp[(size_t)i * WW]; s += t; s2 += t * t; }
    red[0][part][wl] = s; red[1][part][wl] = s2;
    __syncthreads();
    if (part == 0) {
        float S  = red[0][0][wl] + red[0][1][wl] + red[0][2][wl] + red[0][3][wl];
        float S2 = red[1][0][wl] + red[1][1][wl] + red[1][2][wl] + red[1][3][wl];
        float m = S * (1.f / FF);
        float v = S2 * (1.f / FF) - m * m;
        mr[0][wl] = m; mr[1][wl] = rsqrtf(v + 1e-5f);
    }
    __syncthreads();
    float m = mr[0][wl], r = mr[1][wl];
    const float* gp = g + c * FF + part * 64;
    const float* bp = bta + c * FF + part * 64;
    unsigned short* op = out + ((size_t)bc * WW + w) * FF + part * 64;
    for (int i8 = 0; i8 < 8; ++i8) {
        us8 pk;
#pragma unroll
        for (int e = 0; e < 8; ++e) {
            int i = i8 * 8 + e;
            pk[e] = f2bf((xp[(size_t)i * WW] - m) * r * gp[i] + bp[i]);
        }
        *(us8*)(op + i8 * 8) = pk;
    }
}

// ---------------- MFMA conv3x3 (unchanged) ----------------
__global__ __launch_bounds__(256) void conv3_mfma(
    const unsigned short* __restrict__ n1, const unsigned short* __restrict__ Aw,
    unsigned short* __restrict__ oq, unsigned short* __restrict__ ok,
    unsigned short* __restrict__ ov) {
    __shared__ __align__(16) unsigned short Xl[6][68][16];
    const int b = blockIdx.z;
    const int f0 = blockIdx.y * 4;
    const int w0 = blockIdx.x * 64;
    const int tx = threadIdx.x;
    const int lane = tx & 63, wid = tx >> 6;
    const int lr = lane & 15, lg = lane >> 4;
    {
        uint4 z{0, 0, 0, 0};
        for (int i = tx; i < 816; i += 256) ((uint4*)Xl)[i] = z;
    }
    __syncthreads();
    for (int task = tx; task < 960; task += 256) {
        int c = task % 10;
        int fr = (task / 10) % 6;
        int ci = task / 60;
        int fy = f0 - 1 + fr;
        int wx = w0 - 8 + c * 8;
        if (fy >= 0 && fy < FF && wx >= 0 && wx <= WW - 8) {
            us8 v = *(const us8*)(n1 + ((size_t)(b * CC + ci) * FF + fy) * WW + wx);
#pragma unroll
            for (int e = 0; e < 8; ++e) {
                int wl = c * 8 + e - 7;
                if (wl >= 0 && wl < 66) Xl[fr][wl][ci] = v[e];
            }
        }
    }
    __syncthreads();
    bf16x8 A[3][5];
#pragma unroll
    for (int t3 = 0; t3 < 3; ++t3)
#pragma unroll
        for (int t = 0; t < 5; ++t)
            A[t3][t] = *(const bf16x8*)(Aw + ((t3 * 5 + t) * 16 + lr) * 32 + lg * 8);
    const bool h = (lane & 32) != 0;
    int doff[5];
    doff[0] = (h ? (-68 * 32) : ((-68 - 1) * 32));
    doff[1] = (h ? (-1 * 32) : ((-68 + 1) * 32));
    doff[2] = (h ? (1 * 32) : 0);
    doff[3] = (h ? (68 * 32) : ((68 - 1) * 32));
    doff[4] = ((68 + 1) * 32);
    const int fl = wid + 1;
    const int fglob = f0 + wid;
    char* xbase = (char*)Xl + (fl * 68 + 1) * 32 + ((lg & 1) ? 16 : 0);
#pragma unroll
    for (int pt = 0; pt < 4; ++pt) {
        char* bb = xbase + (pt * 16 + lr) * 32;
        bf16x8 Bf[5];
#pragma unroll
        for (int t = 0; t < 5; ++t) Bf[t] = *(const bf16x8*)(bb + doff[t]);
        f32x4 aq = {0.f, 0.f, 0.f, 0.f}, ak = {0.f, 0.f, 0.f, 0.f}, av = {0.f, 0.f, 0.f, 0.f};
#pragma unroll
        for (int t = 0; t < 5; ++t) {
            aq = mfma16(A[0][t], Bf[t], aq);
            ak = mfma16(A[1][t], Bf[t], ak);
            av = mfma16(A[2][t], Bf[t], av);
        }
        int w = w0 + pt * 16 + lr;
#pragma unroll
        for (int r = 0; r < 4; ++r) {
            int co = lg * 4 + r;
            size_t o = ((size_t)(b * CC + co) * FF + fglob) * WW + w;
            oq[o] = f2bf(aq[r]);
            ok[o] = f2bf(ak[r]);
            ov[o] = f2bf(av[r]);
        }
    }
}

// ---------------- 64x128-tile MFMA GEMM, global_load_lds staging ----------------
// LDS image identical to r8 (read-side swizzle unchanged): source is pre-swizzled.
template <int K, int BSRC, int MODE, int NT>
__global__ __launch_bounds__(256, 3) void mgemm3(
    const unsigned short* __restrict__ Wb, const unsigned short* __restrict__ T,
    unsigned short* __restrict__ ob, float* __restrict__ of) {
    constexpr int M = 256;
    __shared__ __align__(16) unsigned short Al[64 * 64];
    __shared__ __align__(16) unsigned short Bl[128 * 64];
    const int id = blockIdx.x;
    const int grp = ((id >> 5) << 3) | (id & 7);
    const int g = (id >> 3) & 3;
    const int t = (NT > 1) ? (grp >> 7) : 0;
    const int rem = grp & 127;
    const int bc = rem >> 2, z = rem & 3;
    const int c = bc & 15;
    const int G0 = g * 64, W0 = z * 128;
    const int tx = threadIdx.x;
    const int lane = tx & 63, wid = tx >> 6;
    const int lr = lane & 15, lg = lane >> 4;
    const int wr = wid >> 1, wc = wid & 1;
    const unsigned short* Ab = Wb + (size_t)t * 1048576 + ((size_t)c * M + G0) * K;
    const unsigned short* Tt = T + (size_t)t * 4194304;
    f32x4 acc[2][4];
#pragma unroll
    for (int i = 0; i < 2; ++i)
#pragma unroll
        for (int j = 0; j < 4; ++j) acc[i][j] = (f32x4){0.f, 0.f, 0.f, 0.f};

    // per-lane pre-swizzled source cols
    const int arow0 = tx >> 3;
    const int aseg0 = (tx & 7) ^ (arow0 & 7);
    const int bsegx = (tx & 7) ^ (arow0 & 7) ^ ((arow0 >> 3) & 7);

    for (int f0 = 0; f0 < K; f0 += 64) {
        // stage A (64 x 64): rows tx>>3 and +32
#pragma unroll
        for (int rep = 0; rep < 2; ++rep) {
            int row = arow0 + rep * 32;
            int seg = (tx & 7) ^ (row & 7);
            gload16(Ab + (size_t)row * K + f0 + seg * 8,
                    (char*)Al + wid * 1024 + rep * 4096);
        }
        if (BSRC == 0) {
            const unsigned short* Tb = Tt + ((size_t)bc * WW + W0) * K;
#pragma unroll
            for (int rep = 0; rep < 4; ++rep) {
                int row = arow0 + rep * 32;
                int seg = (tx & 7) ^ (row & 7) ^ ((row >> 3) & 7);
                gload16(Tb + (size_t)row * K + f0 + seg * 8,
                        (char*)Bl + wid * 1024 + rep * 4096);
            }
        } else {
            const unsigned short* Tb = Tt + (size_t)bc * K * WW;
            const int wseg = tx & 15, fgrp = tx >> 4;
            us8 tv[4];
#pragma unroll
            for (int i = 0; i < 4; ++i)
                tv[i] = *(const us8*)(Tb + (size_t)(f0 + fgrp * 4 + i) * WW + W0 + wseg * 8);
#pragma unroll
            for (int j = 0; j < 8; ++j) {
                int w = wseg * 8 + j;
                us4 p; p.x = tv[0][j]; p.y = tv[1][j]; p.z = tv[2][j]; p.w = tv[3][j];
                *(us4*)((char*)Bl + w * 128 +
                        ((((fgrp >> 1) ^ (w & 7) ^ ((w >> 3) & 7)) << 4)) + (fgrp & 1) * 8) = p;
            }
        }
        __syncthreads();
#pragma unroll
        for (int kc = 0; kc < 2; ++kc) {
            bf16x8 af[2], bf[4];
#pragma unroll
            for (int i = 0; i < 2; ++i) {
                int gr = wr * 32 + i * 16 + lr;
                af[i] = *(const bf16x8*)((char*)Al + gr * 128 +
                        (((kc * 4 + lg) ^ (gr & 7)) << 4));
            }
#pragma unroll
            for (int j = 0; j < 4; ++j) {
                int wrw = wc * 64 + j * 16 + lr;
                bf[j] = *(const bf16x8*)((char*)Bl + wrw * 128 +
                        (((kc * 4 + lg) ^ (wrw & 7) ^ ((wrw >> 3) & 7)) << 4));
            }
#pragma unroll
            for (int i = 0; i < 2; ++i)
#pragma unroll
                for (int j = 0; j < 4; ++j)
                    acc[i][j] = mfma16(af[i], bf[j], acc[i][j]);
        }
        __syncthreads();
    }
#pragma unroll
    for (int i = 0; i < 2; ++i)
#pragma unroll
        for (int j = 0; j < 4; ++j) {
            int g2 = G0 + wr * 32 + i * 16 + lg * 4;
            int w = W0 + wc * 64 + j * 16 + lr;
#pragma unroll
            for (int r = 0; r < 4; ++r) {
                size_t o = (size_t)t * 4194304 + ((size_t)bc * M + g2 + r) * WW + w;
                if (MODE == 0) ob[o] = f2bf(acc[i][j][r]);
                else of[o] += acc[i][j][r];
            }
        }
}

// ---------------- 128x128-tile MFMA GEMM (FFN-up), global_load_lds staging ----------------
template <int K, int M, int MODE>
__global__ __launch_bounds__(256, 2) void mgemm2(
    const unsigned short* __restrict__ Wb, const unsigned short* __restrict__ T,
    unsigned short* __restrict__ ob, float* __restrict__ of) {
    __shared__ __align__(16) unsigned short Al[128 * 64];
    __shared__ __align__(16) unsigned short Bl[128 * 64];
    const int id = blockIdx.x;
    const int grp = ((id >> 6) << 3) | (id & 7);
    const int g = (id >> 3) & 7;
    const int bc = grp >> 2, z = grp & 3;
    const int c = bc & 15;
    const int G0 = g * 128, W0 = z * 128;
    const int tx = threadIdx.x;
    const int lane = tx & 63, wid = tx >> 6;
    const int lr = lane & 15, lg = lane >> 4;
    const int wr = wid >> 1, wc = wid & 1;
    const unsigned short* Ab = Wb + ((size_t)c * M + G0) * K;
    f32x4 acc[4][4];
#pragma unroll
    for (int i = 0; i < 4; ++i)
#pragma unroll
        for (int j = 0; j < 4; ++j) acc[i][j] = (f32x4){0.f, 0.f, 0.f, 0.f};

    const int arow0 = tx >> 3;

    for (int f0 = 0; f0 < K; f0 += 64) {
#pragma unroll
        for (int rep = 0; rep < 4; ++rep) {
            int row = arow0 + rep * 32;
            int seg = (tx & 7) ^ (row & 7);
            gload16(Ab + (size_t)row * K + f0 + seg * 8,
                    (char*)Al + wid * 1024 + rep * 4096);
        }
        {
            const unsigned short* Tb = T + ((size_t)bc * WW + W0) * K;
#pragma unroll
            for (int rep = 0; rep < 4; ++rep) {
                int row = arow0 + rep * 32;
                int seg = (tx & 7) ^ (row & 7) ^ ((row >> 3) & 7);
                gload16(Tb + (size_t)row * K + f0 + seg * 8,
                        (char*)Bl + wid * 1024 + rep * 4096);
            }
        }
        __syncthreads();
#pragma unroll
        for (int kc = 0; kc < 2; ++kc) {
            bf16x8 af[4], bf[4];
#pragma unroll
            for (int i = 0; i < 4; ++i) {
                int gr = wr * 64 + i * 16 + lr;
                af[i] = *(const bf16x8*)((char*)Al + gr * 128 +
                        (((kc * 4 + lg) ^ (gr & 7)) << 4));
                int wrw = wc * 64 + i * 16 + lr;
                bf[i] = *(const bf16x8*)((char*)Bl + wrw * 128 +
                        (((kc * 4 + lg) ^ (wrw & 7) ^ ((wrw >> 3) & 7)) << 4));
            }
#pragma unroll
            for (int i = 0; i < 4; ++i)
#pragma unroll
                for (int j = 0; j < 4; ++j)
                    acc[i][j] = mfma16(af[i], bf[j], acc[i][j]);
        }
        __syncthreads();
    }
#pragma unroll
    for (int i = 0; i < 4; ++i)
#pragma unroll
        for (int j = 0; j < 4; ++j) {
            int gg = G0 + wr * 64 + i * 16 + lg * 4;
            int w = W0 + wc * 64 + j * 16 + lr;
            if (MODE == 2) {
                us4 pk;
                pk.x = f2bf(acc[i][j][0]); pk.y = f2bf(acc[i][j][1]);
                pk.z = f2bf(acc[i][j][2]); pk.w = f2bf(acc[i][j][3]);
                *(us4*)(ob + ((size_t)bc * WW + w) * M + gg) = pk;
            } else {
#pragma unroll
                for (int r = 0; r < 4; ++r) {
                    size_t o = ((size_t)bc * M + gg + r) * WW + w;
                    if (MODE == 0) ob[o] = f2bf(acc[i][j][r]);
                    else of[o] += acc[i][j][r];
                }
            }
        }
}

// ---------------- fused attention v3 (unchanged) ----------------
__global__ __launch_bounds__(256, 2) void attn_fused(
    const unsigned short* __restrict__ qb, const unsigned short* __restrict__ kb,
    const unsigned short* __restrict__ vb, float* __restrict__ qko,
    unsigned short* __restrict__ abT) {
    __shared__ unsigned short Kl[512 * 32];
    __shared__ unsigned short Vl[32 * 512];
    __shared__ unsigned short Ql[64 * 32];
    const int bch = blockIdx.x, qt = blockIdx.y;
    const int bc = bch >> 3, h = bch & 7;
    const int tx = threadIdx.x;
    const int lane = tx & 63, wid = tx >> 6;
    const int lr = lane & 15, lg = lane >> 4;

    const unsigned short* kbase = kb + ((size_t)bc * FF + h * DH) * WW;
    const unsigned short* vbase = vb + ((size_t)bc * FF + h * DH) * WW;
    const unsigned short* qbase = qb + ((size_t)bc * FF + h * DH) * WW + qt * 64;

    {
        int d0 = ((tx >> 3) & 7) * 4;
#pragma unroll
        for (int rep = 0; rep < 2; ++rep) {
            int kw0 = (tx & 7) * 8 + ((tx >> 6) & 3) * 64 + rep * 256;
            us8 v0 = *(const us8*)(kbase + (size_t)(d0 + 0) * WW + kw0);
            us8 v1 = *(const us8*)(kbase + (size_t)(d0 + 1) * WW + kw0);
            us8 v2 = *(const us8*)(kbase + (size_t)(d0 + 2) * WW + kw0);
            us8 v3 = *(const us8*)(kbase + (size_t)(d0 + 3) * WW + kw0);
#pragma unroll
            for (int j = 0; j < 8; ++j) {
                int kw = kw0 + j;
                us4 p; p.x = v0[j]; p.y = v1[j]; p.z = v2[j]; p.w = v3[j];
                *(us4*)((char*)Kl + kw * 64 + ((d0 * 2) ^ ((kw & 3) << 4))) = p;
            }
        }
    }
    {
        int d = tx >> 3;
        int sw = (d & 7) << 4;
#pragma unroll
        for (int rep = 0; rep < 8; ++rep) {
            int kw0 = (tx & 7) * 8 + rep * 64;
            us8 tv = *(const us8*)(vbase + (size_t)d * WW + kw0);
            *(us8*)((char*)Vl + d * 1024 + ((kw0 * 2) ^ sw)) = tv;
        }
    }
    if (tx < 64) {
        int d0 = ((tx >> 3) & 7) * 4;
        int q0 = (tx & 7) * 8;
        us8 v0 = *(const us8*)(qbase + (size_t)(d0 + 0) * WW + q0);
        us8 v1 = *(const us8*)(qbase + (size_t)(d0 + 1) * WW + q0);
        us8 v2 = *(const us8*)(qbase + (size_t)(d0 + 2) * WW + q0);
        us8 v3 = *(const us8*)(qbase + (size_t)(d0 + 3) * WW + q0);
#pragma unroll
        for (int j = 0; j < 8; ++j) {
            us4 p; p.x = v0[j]; p.y = v1[j]; p.z = v2[j]; p.w = v3[j];
            *(us4*)(&Ql[(q0 + j) * 32 + d0]) = p;
        }
    }
    __syncthreads();

    const int q0w = wid * 16;
    bf16x8 qf = *(const bf16x8*)((char*)Ql + (q0w + lr) * 64 + lg * 16);
    f32x4 s[32];
#pragma unroll
    for (int i = 0; i < 32; ++i) s[i] = (f32x4){0.f, 0.f, 0.f, 0.f};
#pragma unroll
    for (int kwt = 0; kwt < 32; ++kwt) {
        int krow = kwt * 16 + lr;
        bf16x8 kf = *(const bf16x8*)((char*)Kl + krow * 64 + ((lg * 16) ^ ((krow & 3) << 4)));
        s[kwt] = mfma16(kf, qf, s[kwt]);
    }
    float mx = -3.0e38f;
    float* qrow = qko + ((size_t)bch * WW + qt * 64 + q0w + lr) * WW;
#pragma unroll
    for (int kwt = 0; kwt < 32; ++kwt) {
        s[kwt] *= 0.0625f;
        float4 st;
        st.x = s[kwt][0]; st.y = s[kwt][1]; st.z = s[kwt][2]; st.w = s[kwt][3];
        *(float4*)(qrow + kwt * 16 + lg * 4) = st;
        mx = fmaxf(mx, fmaxf(fmaxf(st.x, st.y), fmaxf(st.z, st.w)));
    }
    mx = fmaxf(mx, __shfl_xor(mx, 16));
    mx = fmaxf(mx, __shfl_xor(mx, 32));
    float sum = 0.f;
#pragma unroll
    for (int kwt = 0; kwt < 32; ++kwt) {
#pragma unroll
        for (int r = 0; r < 4; ++r) {
            float p = __expf(s[kwt][r] - mx);
            s[kwt][r] = p;
            sum += p;
        }
    }
    sum += __shfl_xor(sum, 16);
    sum += __shfl_xor(sum, 32);
    float inv = 1.0f / sum;

    f32x4 av[2];
    av[0] = (f32x4){0.f, 0.f, 0.f, 0.f};
    av[1] = (f32x4){0.f, 0.f, 0.f, 0.f};
#pragma unroll
    for (int t = 0; t < 16; ++t) {
        unsigned pa0 = f2bf(s[2 * t][0]) | ((unsigned)f2bf(s[2 * t][1]) << 16);
        unsigned pa1 = f2bf(s[2 * t][2]) | ((unsigned)f2bf(s[2 * t][3]) << 16);
        unsigned pb0 = f2bf(s[2 * t + 1][0]) | ((unsigned)f2bf(s[2 * t + 1][1]) << 16);
        unsigned pb1 = f2bf(s[2 * t + 1][2]) | ((unsigned)f2bf(s[2 * t + 1][3]) << 16);
        unsigned s16_0 = (lg == 1) ? pa0 : pb0, s16_1 = (lg == 1) ? pa1 : pb1;
        unsigned s32_0 = (lg == 3) ? pa0 : pb0, s32_1 = (lg == 3) ? pa1 : pb1;
        unsigned s48_0 = (lg == 2) ? pa0 : pb0, s48_1 = (lg == 2) ? pa1 : pb1;
        unsigned r16_0 = (unsigned)__shfl_xor((int)s16_0, 16);
        unsigned r16_1 = (unsigned)__shfl_xor((int)s16_1, 16);
        unsigned r32_0 = (unsigned)__shfl_xor((int)s32_0, 32);
        unsigned r32_1 = (unsigned)__shfl_xor((int)s32_1, 32);
        unsigned r48_0 = (unsigned)__shfl_xor((int)s48_0, 48);
        unsigned r48_1 = (unsigned)__shfl_xor((int)s48_1, 48);
        uint4 wv;
        if (lg == 0)      { wv.x = pa0;   wv.y = pa1;   wv.z = r16_0; wv.w = r16_1; }
        else if (lg == 1) { wv.x = r48_0; wv.y = r48_1; wv.z = r32_0; wv.w = r32_1; }
        else if (lg == 2) { wv.x = r32_0; wv.y = r32_1; wv.z = r48_0; wv.w = r48_1; }
        else              { wv.x = r16_0; wv.y = r16_1; wv.z = pb0;  wv.w = pb1; }
        bf16x8 pf = *reinterpret_cast<bf16x8*>(&wv);
#pragma unroll
        for (int di = 0; di < 2; ++di) {
            int vr = di * 16 + lr;
            bf16x8 vf = *(const bf16x8*)((char*)Vl + vr * 1024 + ((t * 64 + lg * 16) ^ ((vr & 7) << 4)));
            av[di] = mfma16(vf, pf, av[di]);
        }
    }
    unsigned short* arow = abT + ((size_t)bc * WW + qt * 64 + q0w + lr) * FF + h * DH;
#pragma unroll
    for (int di = 0; di < 2; ++di) {
        us4 pk;
        pk.x = f2bf(av[di][0] * inv); pk.y = f2bf(av[di][1] * inv);
        pk.z = f2bf(av[di][2] * inv); pk.w = f2bf(av[di][3] * inv);
        *(us4*)(arow + di * 16 + lg * 4) = pk;
    }
}

// ---------------- LDS-tiled depthwise 16-ch mix ----------------
template <int NPC, int MODE>
__global__ __launch_bounds__(256) void dwmix(
    const unsigned short* __restrict__ in, const float* __restrict__ wdw,
    const float* __restrict__ x, float* __restrict__ fo, unsigned short* __restrict__ bo) {
    __shared__ unsigned short L[16][1024];
    int b = blockIdx.y;
    size_t base = (size_t)blockIdx.x * 1024;
    int tx = threadIdx.x;
#pragma unroll
    for (int r = 0; r < 8; ++r) {
        int idx = tx + r * 256;
        int ci = idx >> 7;
        int seg = idx & 127;
        *(us8*)&L[ci][seg * 8] = *(const us8*)(in + ((size_t)(b * 16 + ci)) * NPC + base + seg * 8);
    }
    __syncthreads();
#pragma unroll
    for (int pos = 0; pos < 4; ++pos) {
        int fw = tx + pos * 256;
        float vin[16];
#pragma unroll
        for (int ci = 0; ci < 16; ++ci) vin[ci] = bf2f(L[ci][fw]);
#pragma unroll
        for (int o = 0; o < 16; ++o) {
            float s = 0.f;
#pragma unroll
            for (int ci = 0; ci < 16; ++ci) s += wdw[o * 16 + ci] * vin[ci];
            size_t oi = ((size_t)(b * 16 + o)) * NPC + base + fw;
            if (MODE == 0) fo[oi] = x[oi] + s;
            else { s = fmaxf(s, 0.f); bo[oi] = f2bf(s * s); }
        }
    }
}

extern "C" void kernel_launch(void* const* d_in, const int* in_sizes, int n_in,
                              void* d_out, int out_size, void* d_ws, size_t ws_size,
                              hipStream_t stream) {
    const float* x      = (const float*)d_in[0];
    const float* conv_q = (const float*)d_in[1];
    const float* conv_k = (const float*)d_in[2];
    const float* conv_v = (const float*)d_in[3];
    const float* wq     = (const float*)d_in[4];
    const float* wk     = (const float*)d_in[5];
    const float* wv     = (const float*)d_in[6];
    const float* wo_pw  = (const float*)d_in[7];
    const float* wo_dw  = (const float*)d_in[8];
    const float* g1     = (const float*)d_in[9];
    const float* b1     = (const float*)d_in[10];
    const float* g2     = (const float*)d_in[11];
    const float* b2     = (const float*)d_in[12];
    const float* w1_pw  = (const float*)d_in[13];
    const float* w1_dw  = (const float*)d_in[14];
    const float* w2_pw  = (const float*)d_in[15];

    float* hout  = (float*)d_out;
    float* qkout = (float*)d_out + 4194304;

    char* ws = (char*)d_ws;
    const size_t MB1 = (size_t)1 << 20;
    unsigned short* n1   = (unsigned short*)(ws + 0 * MB1);
    unsigned short* cq   = (unsigned short*)(ws + 8 * MB1);    // cq/ck/cv contiguous
    unsigned short* qb   = (unsigned short*)(ws + 32 * MB1);   // qb/kb/vb contiguous
    unsigned short* kb   = (unsigned short*)(ws + 40 * MB1);
    unsigned short* vb   = (unsigned short*)(ws + 48 * MB1);
    unsigned short* abT  = (unsigned short*)(ws + 56 * MB1);
    unsigned short* pwb  = (unsigned short*)(ws + 64 * MB1);
    unsigned short* n2t  = (unsigned short*)(ws + 72 * MB1);
    unsigned short* u1t  = (unsigned short*)(ws + 80 * MB1);   // 32 MB
    unsigned short* u2t  = (unsigned short*)(ws + 112 * MB1);  // 32 MB
    unsigned short* Wqkv = (unsigned short*)(ws + 144 * MB1);  // 6 MB
    unsigned short* Wo16 = (unsigned short*)(ws + 150 * MB1);  // 2 MB
    unsigned short* W116 = (unsigned short*)(ws + 152 * MB1);  // 8 MB
    unsigned short* W216 = (unsigned short*)(ws + 160 * MB1);  // 8 MB
    unsigned short* Awb  = (unsigned short*)(ws + 168 * MB1);  // 15 KB

    prep_ln<<<dim3(6430), 256, 0, stream>>>(x, g1, b1, n1,
                                            wq, wk, wv, wo_pw, w1_pw, w2_pw,
                                            conv_q, conv_k, conv_v,
                                            Wqkv, Wo16, W116, W216, Awb);
    conv3_mfma<<<dim3(8, 64, BB), 256, 0, stream>>>(n1, Awb, cq, cq + 4194304, cq + 8388608);
    mgemm3<256, 1, 0, 3><<<dim3(1536), 256, 0, stream>>>(Wqkv, cq, qb, nullptr);
    attn_fused<<<dim3(BC * HH, 8), 256, 0, stream>>>(qb, kb, vb, qkout, abT);
    mgemm3<256, 0, 0, 1><<<dim3(512), 256, 0, stream>>>(Wo16, abT, pwb, nullptr);
    dwmix<131072, 0><<<dim3(128, BB), 256, 0, stream>>>(pwb, wo_dw, x, hout, nullptr);
    ln2t_kernel<<<dim3(BC, 8), 256, 0, stream>>>(hout, g2, b2, n2t);
    mgemm2<256, 1024, 2><<<dim3(1024), 256, 0, stream>>>(W116, n2t, u1t, nullptr);
    dwmix<524288, 1><<<dim3(512, BB), 256, 0, stream>>>(u1t, w1_dw, nullptr, nullptr, u2t);
    mgemm3<1024, 0, 1, 1><<<dim3(512), 256, 0, stream>>>(W216, u2t, nullptr, hout);
}

// Round 10
// 269.206 us; speedup vs baseline: 1.3998x; 1.0448x over previous
//
#include <hip/hip_runtime.h>

#define BB 2
#define CC 16
#define BC 32
#define FF 256
#define WW 512
#define HH 8
#define DH 32

using bf16x8 = __attribute__((ext_vector_type(8))) __bf16;
using f32x4  = __attribute__((ext_vector_type(4))) float;
using us8    = __attribute__((ext_vector_type(8))) unsigned short;
using us4    = __attribute__((ext_vector_type(4))) unsigned short;

#define AS1 __attribute__((address_space(1)))
#define AS3 __attribute__((address_space(3)))

__device__ __forceinline__ float bf2f(unsigned short u) {
    union { unsigned int i; float f; } x; x.i = ((unsigned int)u) << 16; return x.f;
}
__device__ __forceinline__ unsigned short f2bf(float f) {
    union { float f; unsigned int i; } x; x.f = f;
    unsigned int r = x.i + 0x7fffu + ((x.i >> 16) & 1u);   // round-nearest-even
    return (unsigned short)(r >> 16);
}
__device__ __forceinline__ f32x4 mfma16(bf16x8 a, bf16x8 b, f32x4 c) {
    return __builtin_amdgcn_mfma_f32_16x16x32_bf16(a, b, c, 0, 0, 0);
}
__device__ __forceinline__ void gload16(const void* g, void* l) {
    __builtin_amdgcn_global_load_lds((AS1 void*)g, (AS3 void*)l, 16, 0, 0);
}

// ---------------- prep (weight cvt + conv repack) fused with LayerNorm1 ----------------
__global__ __launch_bounds__(256) void prep_ln(
    const float* __restrict__ x, const float* __restrict__ g1,
    const float* __restrict__ b1, unsigned short* __restrict__ n1,
    const float* __restrict__ wq, const float* __restrict__ wk,
    const float* __restrict__ wv, const float* __restrict__ wo,
    const float* __restrict__ w1, const float* __restrict__ w2,
    const float* __restrict__ cwq, const float* __restrict__ cwk,
    const float* __restrict__ cwv,
    unsigned short* __restrict__ Wqkv, unsigned short* __restrict__ Wo16,
    unsigned short* __restrict__ W116, unsigned short* __restrict__ W216,
    unsigned short* __restrict__ Aw) {
    __shared__ float red[2][4][64];
    __shared__ float mr[2][64];
    int bid = blockIdx.x;
    if (bid < 256) {
        int bc = bid & 31, c = bc & 15;
        int part = threadIdx.x >> 6, wl = threadIdx.x & 63;
        int w = (bid >> 5) * 64 + wl;
        const float* xp = x + ((size_t)bc * FF + part * 64) * WW + w;
        float s = 0.f, s2 = 0.f;
#pragma unroll 4
        for (int i = 0; i < 64; ++i) { float t = xp[(size_t)i * WW]; s += t; s2 += t * t; }
        red[0][part][wl] = s; red[1][part][wl] = s2;
        __syncthreads();
        if (part == 0) {
            float S  = red[0][0][wl] + red[0][1][wl] + red[0][2][wl] + red[0][3][wl];
            float S2 = red[1][0][wl] + red[1][1][wl] + red[1][2][wl] + red[1][3][wl];
            float m = S * (1.f / FF);
            float v = S2 * (1.f / FF) - m * m;
            mr[0][wl] = m; mr[1][wl] = rsqrtf(v + 1e-5f);
        }
        __syncthreads();
        float m = mr[0][wl], r = mr[1][wl];
        const float* gp = g1 + c * FF + part * 64;
        const float* bp = b1 + c * FF + part * 64;
        unsigned short* op = n1 + ((size_t)bc * FF + part * 64) * WW + w;
#pragma unroll 4
        for (int i = 0; i < 64; ++i)
            op[(size_t)i * WW] = f2bf((xp[(size_t)i * WW] - m) * r * gp[i] + bp[i]);
    } else if (bid < 256 + 6144) {
        int i = (bid - 256) * 256 + threadIdx.x;
        const float* s; unsigned short* d; int off;
        if (i < 131072)       { s = wq; d = Wqkv;            off = i; }
        else if (i < 262144)  { s = wk; d = Wqkv + 1048576;  off = i - 131072; }
        else if (i < 393216)  { s = wv; d = Wqkv + 2097152;  off = i - 262144; }
        else if (i < 524288)  { s = wo; d = Wo16;            off = i - 393216; }
        else if (i < 1048576) { s = w1; d = W116;            off = i - 524288; }
        else                  { s = w2; d = W216;            off = i - 1048576; }
        const float4* sp = (const float4*)s + (size_t)off * 2;
        float4 a = sp[0], b = sp[1];
        us8 p;
        p[0] = f2bf(a.x); p[1] = f2bf(a.y); p[2] = f2bf(a.z); p[3] = f2bf(a.w);
        p[4] = f2bf(b.x); p[5] = f2bf(b.y); p[6] = f2bf(b.z); p[7] = f2bf(b.w);
        *((us8*)d + off) = p;
    } else {
        int idx = (bid - 256 - 6144) * 256 + threadIdx.x;
        if (idx < 7680) {
            int tensor = idx / 2560;
            int r = idx - tensor * 2560;
            int tp = r >> 9, co = (r >> 5) & 15, k = r & 31;
            int tap = tp * 2 + (k >> 4), ci = k & 15;
            float v = 0.f;
            if (tap < 9) {
                const float* w = tensor == 0 ? cwq : (tensor == 1 ? cwk : cwv);
                v = w[(co * 16 + ci) * 9 + tap];
            }
            Aw[idx] = f2bf(v);
        }
    }
}

// ---------------- LayerNorm, 4-way f-split, transposed out [w][f] ----------------
__global__ __launch_bounds__(256) void ln2t_kernel(
    const float* __restrict__ x, const float* __restrict__ g,
    const float* __restrict__ bta, unsigned short* __restrict__ out) {
    __shared__ float red[2][4][64];
    __shared__ float mr[2][64];
    int bc = blockIdx.x, c = bc & 15;
    int part = threadIdx.x >> 6, wl = threadIdx.x & 63;
    int w = blockIdx.y * 64 + wl;
    const float* xp = x + ((size_t)bc * FF + part * 64) * WW + w;
    float s = 0.f, s2 = 0.f;
#pragma unroll 4
    for (int i = 0; i < 64; ++i) { float t = xp[(size_t)i * WW]; s += t; s2 += t * t; }
    red[0][part][wl] = s; red[1][part][wl] = s2;
    __syncthreads();
    if (part == 0) {
        float S  = red[0][0][wl] + red[0][1][wl] + red[0][2][wl] + red[0][3][wl];
        float S2 = red[1][0][wl] + red[1][1][wl] + red[1][2][wl] + red[1][3][wl];
        float m = S * (1.f / FF);
        float v = S2 * (1.f / FF) - m * m;
        mr[0][wl] = m; mr[1][wl] = rsqrtf(v + 1e-5f);
    }
    __syncthreads();
    float m = mr[0][wl], r = mr[1][wl];
    const float* gp = g + c * FF + part * 64;
    const float* bp = bta + c * FF + part * 64;
    unsigned short* op = out + ((size_t)bc * WW + w) * FF + part * 64;
    for (int i8 = 0; i8 < 8; ++i8) {
        us8 pk;
#pragma unroll
        for (int e = 0; e < 8; ++e) {
            int i = i8 * 8 + e;
            pk[e] = f2bf((xp[(size_t)i * WW] - m) * r * gp[i] + bp[i]);
        }
        *(us8*)(op + i8 * 8) = pk;
    }
}

// ---------------- MFMA conv3x3, faster staging ----------------
__global__ __launch_bounds__(256) void conv3_mfma(
    const unsigned short* __restrict__ n1, const unsigned short* __restrict__ Aw,
    unsigned short* __restrict__ oq, unsigned short* __restrict__ ok,
    unsigned short* __restrict__ ov) {
    __shared__ __align__(16) unsigned short Xl[6][68][16];
    const int b = blockIdx.z;
    const int f0 = blockIdx.y * 4;
    const int w0 = blockIdx.x * 64;
    const int tx = threadIdx.x;
    const int lane = tx & 63, wid = tx >> 6;
    const int lr = lane & 15, lg = lane >> 4;
    {
        uint4 z{0, 0, 0, 0};
        for (int i = tx; i < 816; i += 256) ((uint4*)Xl)[i] = z;
    }
    __syncthreads();
    // stage: 240 tasks = c(10) x fr(6) x cig(4); 4 us8 loads + 8 us4 writes each
    if (tx < 240) {
        int c = tx % 10;
        int fr = (tx / 10) % 6;
        int ci0 = (tx / 60) * 4;
        int fy = f0 - 1 + fr;
        int wx = w0 - 8 + c * 8;
        if (fy >= 0 && fy < FF && wx >= 0 && wx <= WW - 8) {
            const unsigned short* base = n1 + ((size_t)(b * CC + ci0) * FF + fy) * WW + wx;
            us8 v0 = *(const us8*)(base);
            us8 v1 = *(const us8*)(base + (size_t)FF * WW);
            us8 v2 = *(const us8*)(base + (size_t)2 * FF * WW);
            us8 v3 = *(const us8*)(base + (size_t)3 * FF * WW);
            if (c >= 1 && c <= 8) {
#pragma unroll
                for (int e = 0; e < 8; ++e) {
                    int wl = c * 8 + e - 7;
                    us4 p; p.x = v0[e]; p.y = v1[e]; p.z = v2[e]; p.w = v3[e];
                    *(us4*)(&Xl[fr][wl][ci0]) = p;
                }
            } else {
#pragma unroll
                for (int e = 0; e < 8; ++e) {
                    int wl = c * 8 + e - 7;
                    if (wl >= 0 && wl < 66) {
                        us4 p; p.x = v0[e]; p.y = v1[e]; p.z = v2[e]; p.w = v3[e];
                        *(us4*)(&Xl[fr][wl][ci0]) = p;
                    }
                }
            }
        }
    }
    __syncthreads();
    bf16x8 A[3][5];
#pragma unroll
    for (int t3 = 0; t3 < 3; ++t3)
#pragma unroll
        for (int t = 0; t < 5; ++t)
            A[t3][t] = *(const bf16x8*)(Aw + ((t3 * 5 + t) * 16 + lr) * 32 + lg * 8);
    const bool h = (lane & 32) != 0;
    int doff[5];
    doff[0] = (h ? (-68 * 32) : ((-68 - 1) * 32));
    doff[1] = (h ? (-1 * 32) : ((-68 + 1) * 32));
    doff[2] = (h ? (1 * 32) : 0);
    doff[3] = (h ? (68 * 32) : ((68 - 1) * 32));
    doff[4] = ((68 + 1) * 32);
    const int fl = wid + 1;
    const int fglob = f0 + wid;
    char* xbase = (char*)Xl + (fl * 68 + 1) * 32 + ((lg & 1) ? 16 : 0);
#pragma unroll
    for (int pt = 0; pt < 4; ++pt) {
        char* bb = xbase + (pt * 16 + lr) * 32;
        bf16x8 Bf[5];
#pragma unroll
        for (int t = 0; t < 5; ++t) Bf[t] = *(const bf16x8*)(bb + doff[t]);
        f32x4 aq = {0.f, 0.f, 0.f, 0.f}, ak = {0.f, 0.f, 0.f, 0.f}, av = {0.f, 0.f, 0.f, 0.f};
#pragma unroll
        for (int t = 0; t < 5; ++t) {
            aq = mfma16(A[0][t], Bf[t], aq);
            ak = mfma16(A[1][t], Bf[t], ak);
            av = mfma16(A[2][t], Bf[t], av);
        }
        int w = w0 + pt * 16 + lr;
#pragma unroll
        for (int r = 0; r < 4; ++r) {
            int co = lg * 4 + r;
            size_t o = ((size_t)(b * CC + co) * FF + fglob) * WW + w;
            oq[o] = f2bf(aq[r]);
            ok[o] = f2bf(ak[r]);
            ov[o] = f2bf(av[r]);
        }
    }
}

// ---------------- 64x128-tile MFMA GEMM, 4 blocks/CU ----------------
template <int K, int BSRC, int MODE, int NT>
__global__ __launch_bounds__(256, 4) void mgemm3(
    const unsigned short* __restrict__ Wb, const unsigned short* __restrict__ T,
    unsigned short* __restrict__ ob, float* __restrict__ of) {
    constexpr int M = 256;
    __shared__ __align__(16) unsigned short Al[64 * 64];
    __shared__ __align__(16) unsigned short Bl[128 * 64];
    const int id = blockIdx.x;
    const int grp = ((id >> 5) << 3) | (id & 7);
    const int g = (id >> 3) & 3;
    const int t = (NT > 1) ? (grp >> 7) : 0;
    const int rem = grp & 127;
    const int bc = rem >> 2, z = rem & 3;
    const int c = bc & 15;
    const int G0 = g * 64, W0 = z * 128;
    const int tx = threadIdx.x;
    const int lane = tx & 63, wid = tx >> 6;
    const int lr = lane & 15, lg = lane >> 4;
    const int wr = wid >> 1, wc = wid & 1;
    const unsigned short* Ab = Wb + (size_t)t * 1048576 + ((size_t)c * M + G0) * K;
    const unsigned short* Tt = T + (size_t)t * 4194304;
    f32x4 acc[2][4];
#pragma unroll
    for (int i = 0; i < 2; ++i)
#pragma unroll
        for (int j = 0; j < 4; ++j) acc[i][j] = (f32x4){0.f, 0.f, 0.f, 0.f};

    const int arow0 = tx >> 3;

    for (int f0 = 0; f0 < K; f0 += 64) {
#pragma unroll
        for (int rep = 0; rep < 2; ++rep) {
            int row = arow0 + rep * 32;
            int seg = (tx & 7) ^ (row & 7);
            gload16(Ab + (size_t)row * K + f0 + seg * 8,
                    (char*)Al + wid * 1024 + rep * 4096);
        }
        if (BSRC == 0) {
            const unsigned short* Tb = Tt + ((size_t)bc * WW + W0) * K;
#pragma unroll
            for (int rep = 0; rep < 4; ++rep) {
                int row = arow0 + rep * 32;
                int seg = (tx & 7) ^ (row & 7) ^ ((row >> 3) & 7);
                gload16(Tb + (size_t)row * K + f0 + seg * 8,
                        (char*)Bl + wid * 1024 + rep * 4096);
            }
        } else {
            const unsigned short* Tb = Tt + (size_t)bc * K * WW;
            const int wseg = tx & 15, fgrp = tx >> 4;
            us8 tv[4];
#pragma unroll
            for (int i = 0; i < 4; ++i)
                tv[i] = *(const us8*)(Tb + (size_t)(f0 + fgrp * 4 + i) * WW + W0 + wseg * 8);
#pragma unroll
            for (int j = 0; j < 8; ++j) {
                int w = wseg * 8 + j;
                us4 p; p.x = tv[0][j]; p.y = tv[1][j]; p.z = tv[2][j]; p.w = tv[3][j];
                *(us4*)((char*)Bl + w * 128 +
                        ((((fgrp >> 1) ^ (w & 7) ^ ((w >> 3) & 7)) << 4)) + (fgrp & 1) * 8) = p;
            }
        }
        __syncthreads();
#pragma unroll
        for (int kc = 0; kc < 2; ++kc) {
            bf16x8 af[2], bf[4];
#pragma unroll
            for (int i = 0; i < 2; ++i) {
                int gr = wr * 32 + i * 16 + lr;
                af[i] = *(const bf16x8*)((char*)Al + gr * 128 +
                        (((kc * 4 + lg) ^ (gr & 7)) << 4));
            }
#pragma unroll
            for (int j = 0; j < 4; ++j) {
                int wrw = wc * 64 + j * 16 + lr;
                bf[j] = *(const bf16x8*)((char*)Bl + wrw * 128 +
                        (((kc * 4 + lg) ^ (wrw & 7) ^ ((wrw >> 3) & 7)) << 4));
            }
#pragma unroll
            for (int i = 0; i < 2; ++i)
#pragma unroll
                for (int j = 0; j < 4; ++j)
                    acc[i][j] = mfma16(af[i], bf[j], acc[i][j]);
        }
        __syncthreads();
    }
#pragma unroll
    for (int i = 0; i < 2; ++i)
#pragma unroll
        for (int j = 0; j < 4; ++j) {
            int g2 = G0 + wr * 32 + i * 16 + lg * 4;
            int w = W0 + wc * 64 + j * 16 + lr;
#pragma unroll
            for (int r = 0; r < 4; ++r) {
                size_t o = (size_t)t * 4194304 + ((size_t)bc * M + g2 + r) * WW + w;
                if (MODE == 0) ob[o] = f2bf(acc[i][j][r]);
                else of[o] += acc[i][j][r];
            }
        }
}

// ---------------- 128x128-tile MFMA GEMM (FFN-up), coalesced MODE2 epilogue ----------------
template <int K, int M, int MODE>
__global__ __launch_bounds__(256, 2) void mgemm2(
    const unsigned short* __restrict__ Wb, const unsigned short* __restrict__ T,
    unsigned short* __restrict__ ob, float* __restrict__ of) {
    __shared__ __align__(16) unsigned short SH[2][128 * 64];
    unsigned short* Al = SH[0];
    unsigned short* Bl = SH[1];
    const int id = blockIdx.x;
    const int grp = ((id >> 6) << 3) | (id & 7);
    const int g = (id >> 3) & 7;
    const int bc = grp >> 2, z = grp & 3;
    const int c = bc & 15;
    const int G0 = g * 128, W0 = z * 128;
    const int tx = threadIdx.x;
    const int lane = tx & 63, wid = tx >> 6;
    const int lr = lane & 15, lg = lane >> 4;
    const int wr = wid >> 1, wc = wid & 1;
    const unsigned short* Ab = Wb + ((size_t)c * M + G0) * K;
    f32x4 acc[4][4];
#pragma unroll
    for (int i = 0; i < 4; ++i)
#pragma unroll
        for (int j = 0; j < 4; ++j) acc[i][j] = (f32x4){0.f, 0.f, 0.f, 0.f};

    const int arow0 = tx >> 3;

    for (int f0 = 0; f0 < K; f0 += 64) {
#pragma unroll
        for (int rep = 0; rep < 4; ++rep) {
            int row = arow0 + rep * 32;
            int seg = (tx & 7) ^ (row & 7);
            gload16(Ab + (size_t)row * K + f0 + seg * 8,
                    (char*)Al + wid * 1024 + rep * 4096);
        }
        {
            const unsigned short* Tb = T + ((size_t)bc * WW + W0) * K;
#pragma unroll
            for (int rep = 0; rep < 4; ++rep) {
                int row = arow0 + rep * 32;
                int seg = (tx & 7) ^ (row & 7) ^ ((row >> 3) & 7);
                gload16(Tb + (size_t)row * K + f0 + seg * 8,
                        (char*)Bl + wid * 1024 + rep * 4096);
            }
        }
        __syncthreads();
#pragma unroll
        for (int kc = 0; kc < 2; ++kc) {
            bf16x8 af[4], bf[4];
#pragma unroll
            for (int i = 0; i < 4; ++i) {
                int gr = wr * 64 + i * 16 + lr;
                af[i] = *(const bf16x8*)((char*)Al + gr * 128 +
                        (((kc * 4 + lg) ^ (gr & 7)) << 4));
                int wrw = wc * 64 + i * 16 + lr;
                bf[i] = *(const bf16x8*)((char*)Bl + wrw * 128 +
                        (((kc * 4 + lg) ^ (wrw & 7) ^ ((wrw >> 3) & 7)) << 4));
            }
#pragma unroll
            for (int i = 0; i < 4; ++i)
#pragma unroll
                for (int j = 0; j < 4; ++j)
                    acc[i][j] = mfma16(af[i], bf[j], acc[i][j]);
        }
        __syncthreads();
    }
    if (MODE == 2) {
        // bounce through LDS for coalesced [w][g] stores
        char* S = (char*)SH;
#pragma unroll
        for (int i = 0; i < 4; ++i)
#pragma unroll
            for (int j = 0; j < 4; ++j) {
                int wl = wc * 64 + j * 16 + lr;
                int gl = wr * 64 + i * 16 + lg * 4;
                us4 pk;
                pk.x = f2bf(acc[i][j][0]); pk.y = f2bf(acc[i][j][1]);
                pk.z = f2bf(acc[i][j][2]); pk.w = f2bf(acc[i][j][3]);
                *(us4*)(S + wl * 256 + ((gl * 2) ^ ((wl & 7) << 4))) = pk;
            }
        __syncthreads();
        unsigned short* og = ob + ((size_t)bc * WW + W0) * M + G0;
#pragma unroll
        for (int rep = 0; rep < 8; ++rep) {
            int slot = tx + rep * 256;
            int row = slot >> 4, col = slot & 15;
            us8 v = *(const us8*)(S + row * 256 + ((col * 16) ^ ((row & 7) << 4)));
            *(us8*)(og + (size_t)row * M + col * 8) = v;
        }
    } else {
#pragma unroll
        for (int i = 0; i < 4; ++i)
#pragma unroll
            for (int j = 0; j < 4; ++j) {
                int gg = G0 + wr * 64 + i * 16 + lg * 4;
                int w = W0 + wc * 64 + j * 16 + lr;
#pragma unroll
                for (int r = 0; r < 4; ++r) {
                    size_t o = ((size_t)bc * M + gg + r) * WW + w;
                    if (MODE == 0) ob[o] = f2bf(acc[i][j][r]);
                    else of[o] += acc[i][j][r];
                }
            }
    }
}

// ---------------- fused attention v3 (unchanged) ----------------
__global__ __launch_bounds__(256, 2) void attn_fused(
    const unsigned short* __restrict__ qb, const unsigned short* __restrict__ kb,
    const unsigned short* __restrict__ vb, float* __restrict__ qko,
    unsigned short* __restrict__ abT) {
    __shared__ unsigned short Kl[512 * 32];
    __shared__ unsigned short Vl[32 * 512];
    __shared__ unsigned short Ql[64 * 32];
    const int bch = blockIdx.x, qt = blockIdx.y;
    const int bc = bch >> 3, h = bch & 7;
    const int tx = threadIdx.x;
    const int lane = tx & 63, wid = tx >> 6;
    const int lr = lane & 15, lg = lane >> 4;

    const unsigned short* kbase = kb + ((size_t)bc * FF + h * DH) * WW;
    const unsigned short* vbase = vb + ((size_t)bc * FF + h * DH) * WW;
    const unsigned short* qbase = qb + ((size_t)bc * FF + h * DH) * WW + qt * 64;

    {
        int d0 = ((tx >> 3) & 7) * 4;
#pragma unroll
        for (int rep = 0; rep < 2; ++rep) {
            int kw0 = (tx & 7) * 8 + ((tx >> 6) & 3) * 64 + rep * 256;
            us8 v0 = *(const us8*)(kbase + (size_t)(d0 + 0) * WW + kw0);
            us8 v1 = *(const us8*)(kbase + (size_t)(d0 + 1) * WW + kw0);
            us8 v2 = *(const us8*)(kbase + (size_t)(d0 + 2) * WW + kw0);
            us8 v3 = *(const us8*)(kbase + (size_t)(d0 + 3) * WW + kw0);
#pragma unroll
            for (int j = 0; j < 8; ++j) {
                int kw = kw0 + j;
                us4 p; p.x = v0[j]; p.y = v1[j]; p.z = v2[j]; p.w = v3[j];
                *(us4*)((char*)Kl + kw * 64 + ((d0 * 2) ^ ((kw & 3) << 4))) = p;
            }
        }
    }
    {
        int d = tx >> 3;
        int sw = (d & 7) << 4;
#pragma unroll
        for (int rep = 0; rep < 8; ++rep) {
            int kw0 = (tx & 7) * 8 + rep * 64;
            us8 tv = *(const us8*)(vbase + (size_t)d * WW + kw0);
            *(us8*)((char*)Vl + d * 1024 + ((kw0 * 2) ^ sw)) = tv;
        }
    }
    if (tx < 64) {
        int d0 = ((tx >> 3) & 7) * 4;
        int q0 = (tx & 7) * 8;
        us8 v0 = *(const us8*)(qbase + (size_t)(d0 + 0) * WW + q0);
        us8 v1 = *(const us8*)(qbase + (size_t)(d0 + 1) * WW + q0);
        us8 v2 = *(const us8*)(qbase + (size_t)(d0 + 2) * WW + q0);
        us8 v3 = *(const us8*)(qbase + (size_t)(d0 + 3) * WW + q0);
#pragma unroll
        for (int j = 0; j < 8; ++j) {
            us4 p; p.x = v0[j]; p.y = v1[j]; p.z = v2[j]; p.w = v3[j];
            *(us4*)(&Ql[(q0 + j) * 32 + d0]) = p;
        }
    }
    __syncthreads();

    const int q0w = wid * 16;
    bf16x8 qf = *(const bf16x8*)((char*)Ql + (q0w + lr) * 64 + lg * 16);
    f32x4 s[32];
#pragma unroll
    for (int i = 0; i < 32; ++i) s[i] = (f32x4){0.f, 0.f, 0.f, 0.f};
#pragma unroll
    for (int kwt = 0; kwt < 32; ++kwt) {
        int krow = kwt * 16 + lr;
        bf16x8 kf = *(const bf16x8*)((char*)Kl + krow * 64 + ((lg * 16) ^ ((krow & 3) << 4)));
        s[kwt] = mfma16(kf, qf, s[kwt]);
    }
    float mx = -3.0e38f;
    float* qrow = qko + ((size_t)bch * WW + qt * 64 + q0w + lr) * WW;
#pragma unroll
    for (int kwt = 0; kwt < 32; ++kwt) {
        s[kwt] *= 0.0625f;
        float4 st;
        st.x = s[kwt][0]; st.y = s[kwt][1]; st.z = s[kwt][2]; st.w = s[kwt][3];
        *(float4*)(qrow + kwt * 16 + lg * 4) = st;
        mx = fmaxf(mx, fmaxf(fmaxf(st.x, st.y), fmaxf(st.z, st.w)));
    }
    mx = fmaxf(mx, __shfl_xor(mx, 16));
    mx = fmaxf(mx, __shfl_xor(mx, 32));
    float sum = 0.f;
#pragma unroll
    for (int kwt = 0; kwt < 32; ++kwt) {
#pragma unroll
        for (int r = 0; r < 4; ++r) {
            float p = __expf(s[kwt][r] - mx);
            s[kwt][r] = p;
            sum += p;
        }
    }
    sum += __shfl_xor(sum, 16);
    sum += __shfl_xor(sum, 32);
    float inv = 1.0f / sum;

    f32x4 av[2];
    av[0] = (f32x4){0.f, 0.f, 0.f, 0.f};
    av[1] = (f32x4){0.f, 0.f, 0.f, 0.f};
#pragma unroll
    for (int t = 0; t < 16; ++t) {
        unsigned pa0 = f2bf(s[2 * t][0]) | ((unsigned)f2bf(s[2 * t][1]) << 16);
        unsigned pa1 = f2bf(s[2 * t][2]) | ((unsigned)f2bf(s[2 * t][3]) << 16);
        unsigned pb0 = f2bf(s[2 * t + 1][0]) | ((unsigned)f2bf(s[2 * t + 1][1]) << 16);
        unsigned pb1 = f2bf(s[2 * t + 1][2]) | ((unsigned)f2bf(s[2 * t + 1][3]) << 16);
        unsigned s16_0 = (lg == 1) ? pa0 : pb0, s16_1 = (lg == 1) ? pa1 : pb1;
        unsigned s32_0 = (lg == 3) ? pa0 : pb0, s32_1 = (lg == 3) ? pa1 : pb1;
        unsigned s48_0 = (lg == 2) ? pa0 : pb0, s48_1 = (lg == 2) ? pa1 : pb1;
        unsigned r16_0 = (unsigned)__shfl_xor((int)s16_0, 16);
        unsigned r16_1 = (unsigned)__shfl_xor((int)s16_1, 16);
        unsigned r32_0 = (unsigned)__shfl_xor((int)s32_0, 32);
        unsigned r32_1 = (unsigned)__shfl_xor((int)s32_1, 32);
        unsigned r48_0 = (unsigned)__shfl_xor((int)s48_0, 48);
        unsigned r48_1 = (unsigned)__shfl_xor((int)s48_1, 48);
        uint4 wv;
        if (lg == 0)      { wv.x = pa0;   wv.y = pa1;   wv.z = r16_0; wv.w = r16_1; }
        else if (lg == 1) { wv.x = r48_0; wv.y = r48_1; wv.z = r32_0; wv.w = r32_1; }
        else if (lg == 2) { wv.x = r32_0; wv.y = r32_1; wv.z = r48_0; wv.w = r48_1; }
        else              { wv.x = r16_0; wv.y = r16_1; wv.z = pb0;  wv.w = pb1; }
        bf16x8 pf = *reinterpret_cast<bf16x8*>(&wv);
#pragma unroll
        for (int di = 0; di < 2; ++di) {
            int vr = di * 16 + lr;
            bf16x8 vf = *(const bf16x8*)((char*)Vl + vr * 1024 + ((t * 64 + lg * 16) ^ ((vr & 7) << 4)));
            av[di] = mfma16(vf, pf, av[di]);
        }
    }
    unsigned short* arow = abT + ((size_t)bc * WW + qt * 64 + q0w + lr) * FF + h * DH;
#pragma unroll
    for (int di = 0; di < 2; ++di) {
        us4 pk;
        pk.x = f2bf(av[di][0] * inv); pk.y = f2bf(av[di][1] * inv);
        pk.z = f2bf(av[di][2] * inv); pk.w = f2bf(av[di][3] * inv);
        *(us4*)(arow + di * 16 + lg * 4) = pk;
    }
}

// ---------------- LDS-tiled depthwise 16-ch mix ----------------
template <int NPC, int MODE>
__global__ __launch_bounds__(256) void dwmix(
    const unsigned short* __restrict__ in, const float* __restrict__ wdw,
    const float* __restrict__ x, float* __restrict__ fo, unsigned short* __restrict__ bo) {
    __shared__ unsigned short L[16][1024];
    int b = blockIdx.y;
    size_t base = (size_t)blockIdx.x * 1024;
    int tx = threadIdx.x;
#pragma unroll
    for (int r = 0; r < 8; ++r) {
        int idx = tx + r * 256;
        int ci = idx >> 7;
        int seg = idx & 127;
        *(us8*)&L[ci][seg * 8] = *(const us8*)(in + ((size_t)(b * 16 + ci)) * NPC + base + seg * 8);
    }
    __syncthreads();
#pragma unroll
    for (int pos = 0; pos < 4; ++pos) {
        int fw = tx + pos * 256;
        float vin[16];
#pragma unroll
        for (int ci = 0; ci < 16; ++ci) vin[ci] = bf2f(L[ci][fw]);
#pragma unroll
        for (int o = 0; o < 16; ++o) {
            float s = 0.f;
#pragma unroll
            for (int ci = 0; ci < 16; ++ci) s += wdw[o * 16 + ci] * vin[ci];
            size_t oi = ((size_t)(b * 16 + o)) * NPC + base + fw;
            if (MODE == 0) fo[oi] = x[oi] + s;
            else { s = fmaxf(s, 0.f); bo[oi] = f2bf(s * s); }
        }
    }
}

extern "C" void kernel_launch(void* const* d_in, const int* in_sizes, int n_in,
                              void* d_out, int out_size, void* d_ws, size_t ws_size,
                              hipStream_t stream) {
    const float* x      = (const float*)d_in[0];
    const float* conv_q = (const float*)d_in[1];
    const float* conv_k = (const float*)d_in[2];
    const float* conv_v = (const float*)d_in[3];
    const float* wq     = (const float*)d_in[4];
    const float* wk     = (const float*)d_in[5];
    const float* wv     = (const float*)d_in[6];
    const float* wo_pw  = (const float*)d_in[7];
    const float* wo_dw  = (const float*)d_in[8];
    const float* g1     = (const float*)d_in[9];
    const float* b1     = (const float*)d_in[10];
    const float* g2     = (const float*)d_in[11];
    const float* b2     = (const float*)d_in[12];
    const float* w1_pw  = (const float*)d_in[13];
    const float* w1_dw  = (const float*)d_in[14];
    const float* w2_pw  = (const float*)d_in[15];

    float* hout  = (float*)d_out;
    float* qkout = (float*)d_out + 4194304;

    char* ws = (char*)d_ws;
    const size_t MB1 = (size_t)1 << 20;
    unsigned short* n1   = (unsigned short*)(ws + 0 * MB1);
    unsigned short* cq   = (unsigned short*)(ws + 8 * MB1);    // cq/ck/cv contiguous
    unsigned short* qb   = (unsigned short*)(ws + 32 * MB1);   // qb/kb/vb contiguous
    unsigned short* kb   = (unsigned short*)(ws + 40 * MB1);
    unsigned short* vb   = (unsigned short*)(ws + 48 * MB1);
    unsigned short* abT  = (unsigned short*)(ws + 56 * MB1);
    unsigned short* pwb  = (unsigned short*)(ws + 64 * MB1);
    unsigned short* n2t  = (unsigned short*)(ws + 72 * MB1);
    unsigned short* u1t  = (unsigned short*)(ws + 80 * MB1);   // 32 MB
    unsigned short* u2t  = (unsigned short*)(ws + 112 * MB1);  // 32 MB
    unsigned short* Wqkv = (unsigned short*)(ws + 144 * MB1);  // 6 MB
    unsigned short* Wo16 = (unsigned short*)(ws + 150 * MB1);  // 2 MB
    unsigned short* W116 = (unsigned short*)(ws + 152 * MB1);  // 8 MB
    unsigned short* W216 = (unsigned short*)(ws + 160 * MB1);  // 8 MB
    unsigned short* Awb  = (unsigned short*)(ws + 168 * MB1);  // 15 KB

    prep_ln<<<dim3(6430), 256, 0, stream>>>(x, g1, b1, n1,
                                            wq, wk, wv, wo_pw, w1_pw, w2_pw,
                                            conv_q, conv_k, conv_v,
                                            Wqkv, Wo16, W116, W216, Awb);
    conv3_mfma<<<dim3(8, 64, BB), 256, 0, stream>>>(n1, Awb, cq, cq + 4194304, cq + 8388608);
    mgemm3<256, 1, 0, 3><<<dim3(1536), 256, 0, stream>>>(Wqkv, cq, qb, nullptr);
    attn_fused<<<dim3(BC * HH, 8), 256, 0, stream>>>(qb, kb, vb, qkout, abT);
    mgemm3<256, 0, 0, 1><<<dim3(512), 256, 0, stream>>>(Wo16, abT, pwb, nullptr);
    dwmix<131072, 0><<<dim3(128, BB), 256, 0, stream>>>(pwb, wo_dw, x, hout, nullptr);
    ln2t_kernel<<<dim3(BC, 8), 256, 0, stream>>>(hout, g2, b2, n2t);
    mgemm2<256, 1024, 2><<<dim3(1024), 256, 0, stream>>>(W116, n2t, u1t, nullptr);
    dwmix<524288, 1><<<dim3(512, BB), 256, 0, stream>>>(u1t, w1_dw, nullptr, nullptr, u2t);
    mgemm3<1024, 0, 1, 1><<<dim3(512), 256, 0, stream>>>(W216, u2t, nullptr, hout);
}

// Round 11
// 261.669 us; speedup vs baseline: 1.4401x; 1.0288x over previous
//
#include <hip/hip_runtime.h>

#define BB 2
#define CC 16
#define BC 32
#define FF 256
#define WW 512
#define HH 8
#define DH 32

using bf16x8 = __attribute__((ext_vector_type(8))) __bf16;
using f32x4  = __attribute__((ext_vector_type(4))) float;
using us8    = __attribute__((ext_vector_type(8))) unsigned short;
using us4    = __attribute__((ext_vector_type(4))) unsigned short;

#define AS1 __attribute__((address_space(1)))
#define AS3 __attribute__((address_space(3)))

__device__ __forceinline__ float bf2f(unsigned short u) {
    union { unsigned int i; float f; } x; x.i = ((unsigned int)u) << 16; return x.f;
}
__device__ __forceinline__ unsigned short f2bf(float f) {
    union { float f; unsigned int i; } x; x.f = f;
    unsigned int r = x.i + 0x7fffu + ((x.i >> 16) & 1u);   // round-nearest-even
    return (unsigned short)(r >> 16);
}
__device__ __forceinline__ f32x4 mfma16(bf16x8 a, bf16x8 b, f32x4 c) {
    return __builtin_amdgcn_mfma_f32_16x16x32_bf16(a, b, c, 0, 0, 0);
}
__device__ __forceinline__ void gload16(const void* g, void* l) {
    __builtin_amdgcn_global_load_lds((AS1 void*)g, (AS3 void*)l, 16, 0, 0);
}

// ---------------- prep (weight cvt + conv repack) fused with LayerNorm1 ----------------
__global__ __launch_bounds__(256) void prep_ln(
    const float* __restrict__ x, const float* __restrict__ g1,
    const float* __restrict__ b1, unsigned short* __restrict__ n1,
    const float* __restrict__ wq, const float* __restrict__ wk,
    const float* __restrict__ wv, const float* __restrict__ wo,
    const float* __restrict__ w1, const float* __restrict__ w2,
    const float* __restrict__ cwq, const float* __restrict__ cwk,
    const float* __restrict__ cwv,
    unsigned short* __restrict__ Wqkv, unsigned short* __restrict__ Wo16,
    unsigned short* __restrict__ W116, unsigned short* __restrict__ W216,
    unsigned short* __restrict__ Aw) {
    __shared__ float red[2][8][32];
    __shared__ float mr[2][32];
    int bid = blockIdx.x;
    if (bid < 512) {
        int bc = bid & 31, c = bc & 15;
        int part = threadIdx.x >> 5, wl = threadIdx.x & 31;
        int w = (bid >> 5) * 32 + wl;
        const float* xp = x + ((size_t)bc * FF + part * 32) * WW + w;
        float s = 0.f, s2 = 0.f;
#pragma unroll 4
        for (int i = 0; i < 32; ++i) { float t = xp[(size_t)i * WW]; s += t; s2 += t * t; }
        red[0][part][wl] = s; red[1][part][wl] = s2;
        __syncthreads();
        if (part == 0) {
            float S = 0.f, S2 = 0.f;
#pragma unroll
            for (int p = 0; p < 8; ++p) { S += red[0][p][wl]; S2 += red[1][p][wl]; }
            float m = S * (1.f / FF);
            float v = S2 * (1.f / FF) - m * m;
            mr[0][wl] = m; mr[1][wl] = rsqrtf(v + 1e-5f);
        }
        __syncthreads();
        float m = mr[0][wl], r = mr[1][wl];
        const float* gp = g1 + c * FF + part * 32;
        const float* bp = b1 + c * FF + part * 32;
        unsigned short* op = n1 + ((size_t)bc * FF + part * 32) * WW + w;
#pragma unroll 4
        for (int i = 0; i < 32; ++i)
            op[(size_t)i * WW] = f2bf((xp[(size_t)i * WW] - m) * r * gp[i] + bp[i]);
    } else if (bid < 512 + 6144) {
        int i = (bid - 512) * 256 + threadIdx.x;
        const float* s; unsigned short* d; int off;
        if (i < 131072)       { s = wq; d = Wqkv;            off = i; }
        else if (i < 262144)  { s = wk; d = Wqkv + 1048576;  off = i - 131072; }
        else if (i < 393216)  { s = wv; d = Wqkv + 2097152;  off = i - 262144; }
        else if (i < 524288)  { s = wo; d = Wo16;            off = i - 393216; }
        else if (i < 1048576) { s = w1; d = W116;            off = i - 524288; }
        else                  { s = w2; d = W216;            off = i - 1048576; }
        const float4* sp = (const float4*)s + (size_t)off * 2;
        float4 a = sp[0], b = sp[1];
        us8 p;
        p[0] = f2bf(a.x); p[1] = f2bf(a.y); p[2] = f2bf(a.z); p[3] = f2bf(a.w);
        p[4] = f2bf(b.x); p[5] = f2bf(b.y); p[6] = f2bf(b.z); p[7] = f2bf(b.w);
        *((us8*)d + off) = p;
    } else {
        int idx = (bid - 512 - 6144) * 256 + threadIdx.x;
        if (idx < 7680) {
            int tensor = idx / 2560;
            int r = idx - tensor * 2560;
            int tp = r >> 9, co = (r >> 5) & 15, k = r & 31;
            int tap = tp * 2 + (k >> 4), ci = k & 15;
            float v = 0.f;
            if (tap < 9) {
                const float* w = tensor == 0 ? cwq : (tensor == 1 ? cwk : cwv);
                v = w[(co * 16 + ci) * 9 + tap];
            }
            Aw[idx] = f2bf(v);
        }
    }
}

// ---------------- LayerNorm, 8-way f-split, transposed out [w][f] ----------------
__global__ __launch_bounds__(256) void ln2t_kernel(
    const float* __restrict__ x, const float* __restrict__ g,
    const float* __restrict__ bta, unsigned short* __restrict__ out) {
    __shared__ float red[2][8][32];
    __shared__ float mr[2][32];
    int bc = blockIdx.x, c = bc & 15;
    int part = threadIdx.x >> 5, wl = threadIdx.x & 31;
    int w = blockIdx.y * 32 + wl;
    const float* xp = x + ((size_t)bc * FF + part * 32) * WW + w;
    float s = 0.f, s2 = 0.f;
#pragma unroll 4
    for (int i = 0; i < 32; ++i) { float t = xp[(size_t)i * WW]; s += t; s2 += t * t; }
    red[0][part][wl] = s; red[1][part][wl] = s2;
    __syncthreads();
    if (part == 0) {
        float S = 0.f, S2 = 0.f;
#pragma unroll
        for (int p = 0; p < 8; ++p) { S += red[0][p][wl]; S2 += red[1][p][wl]; }
        float m = S * (1.f / FF);
        float v = S2 * (1.f / FF) - m * m;
        mr[0][wl] = m; mr[1][wl] = rsqrtf(v + 1e-5f);
    }
    __syncthreads();
    float m = mr[0][wl], r = mr[1][wl];
    const float* gp = g + c * FF + part * 32;
    const float* bp = bta + c * FF + part * 32;
    unsigned short* op = out + ((size_t)bc * WW + w) * FF + part * 32;
    for (int i8 = 0; i8 < 4; ++i8) {
        us8 pk;
#pragma unroll
        for (int e = 0; e < 8; ++e) {
            int i = i8 * 8 + e;
            pk[e] = f2bf((xp[(size_t)i * WW] - m) * r * gp[i] + bp[i]);
        }
        *(us8*)(op + i8 * 8) = pk;
    }
}

// ---------------- MFMA conv3x3 ----------------
__global__ __launch_bounds__(256) void conv3_mfma(
    const unsigned short* __restrict__ n1, const unsigned short* __restrict__ Aw,
    unsigned short* __restrict__ oq, unsigned short* __restrict__ ok,
    unsigned short* __restrict__ ov) {
    __shared__ __align__(16) unsigned short Xl[6][68][16];
    const int b = blockIdx.z;
    const int f0 = blockIdx.y * 4;
    const int w0 = blockIdx.x * 64;
    const int tx = threadIdx.x;
    const int lane = tx & 63, wid = tx >> 6;
    const int lr = lane & 15, lg = lane >> 4;
    {
        uint4 z{0, 0, 0, 0};
        for (int i = tx; i < 816; i += 256) ((uint4*)Xl)[i] = z;
    }
    __syncthreads();
    if (tx < 240) {
        int c = tx % 10;
        int fr = (tx / 10) % 6;
        int ci0 = (tx / 60) * 4;
        int fy = f0 - 1 + fr;
        int wx = w0 - 8 + c * 8;
        if (fy >= 0 && fy < FF && wx >= 0 && wx <= WW - 8) {
            const unsigned short* base = n1 + ((size_t)(b * CC + ci0) * FF + fy) * WW + wx;
            us8 v0 = *(const us8*)(base);
            us8 v1 = *(const us8*)(base + (size_t)FF * WW);
            us8 v2 = *(const us8*)(base + (size_t)2 * FF * WW);
            us8 v3 = *(const us8*)(base + (size_t)3 * FF * WW);
            if (c >= 1 && c <= 8) {
#pragma unroll
                for (int e = 0; e < 8; ++e) {
                    int wl = c * 8 + e - 7;
                    us4 p; p.x = v0[e]; p.y = v1[e]; p.z = v2[e]; p.w = v3[e];
                    *(us4*)(&Xl[fr][wl][ci0]) = p;
                }
            } else {
#pragma unroll
                for (int e = 0; e < 8; ++e) {
                    int wl = c * 8 + e - 7;
                    if (wl >= 0 && wl < 66) {
                        us4 p; p.x = v0[e]; p.y = v1[e]; p.z = v2[e]; p.w = v3[e];
                        *(us4*)(&Xl[fr][wl][ci0]) = p;
                    }
                }
            }
        }
    }
    __syncthreads();
    bf16x8 A[3][5];
#pragma unroll
    for (int t3 = 0; t3 < 3; ++t3)
#pragma unroll
        for (int t = 0; t < 5; ++t)
            A[t3][t] = *(const bf16x8*)(Aw + ((t3 * 5 + t) * 16 + lr) * 32 + lg * 8);
    const bool h = (lane & 32) != 0;
    int doff[5];
    doff[0] = (h ? (-68 * 32) : ((-68 - 1) * 32));
    doff[1] = (h ? (-1 * 32) : ((-68 + 1) * 32));
    doff[2] = (h ? (1 * 32) : 0);
    doff[3] = (h ? (68 * 32) : ((68 - 1) * 32));
    doff[4] = ((68 + 1) * 32);
    const int fl = wid + 1;
    const int fglob = f0 + wid;
    char* xbase = (char*)Xl + (fl * 68 + 1) * 32 + ((lg & 1) ? 16 : 0);
#pragma unroll
    for (int pt = 0; pt < 4; ++pt) {
        char* bb = xbase + (pt * 16 + lr) * 32;
        bf16x8 Bf[5];
#pragma unroll
        for (int t = 0; t < 5; ++t) Bf[t] = *(const bf16x8*)(bb + doff[t]);
        f32x4 aq = {0.f, 0.f, 0.f, 0.f}, ak = {0.f, 0.f, 0.f, 0.f}, av = {0.f, 0.f, 0.f, 0.f};
#pragma unroll
        for (int t = 0; t < 5; ++t) {
            aq = mfma16(A[0][t], Bf[t], aq);
            ak = mfma16(A[1][t], Bf[t], ak);
            av = mfma16(A[2][t], Bf[t], av);
        }
        int w = w0 + pt * 16 + lr;
#pragma unroll
        for (int r = 0; r < 4; ++r) {
            int co = lg * 4 + r;
            size_t o = ((size_t)(b * CC + co) * FF + fglob) * WW + w;
            oq[o] = f2bf(aq[r]);
            ok[o] = f2bf(ak[r]);
            ov[o] = f2bf(av[r]);
        }
    }
}

// ---------------- 64x128-tile MFMA GEMM, double-buffered 2-phase prefetch ----------------
template <int K, int BSRC, int MODE, int NT>
__global__ __launch_bounds__(256, 3) void mgemm3(
    const unsigned short* __restrict__ Wb, const unsigned short* __restrict__ T,
    unsigned short* __restrict__ ob, float* __restrict__ of) {
    constexpr int M = 256;
    constexpr int NK = K / 64;
    __shared__ __align__(16) unsigned short Al[2][64 * 64];
    __shared__ __align__(16) unsigned short Bl[2][128 * 64];
    const int id = blockIdx.x;
    const int grp = ((id >> 5) << 3) | (id & 7);
    const int g = (id >> 3) & 3;
    const int t = (NT > 1) ? (grp >> 7) : 0;
    const int rem = grp & 127;
    const int bc = rem >> 2, z = rem & 3;
    const int c = bc & 15;
    const int G0 = g * 64, W0 = z * 128;
    const int tx = threadIdx.x;
    const int lane = tx & 63, wid = tx >> 6;
    const int lr = lane & 15, lg = lane >> 4;
    const int wr = wid >> 1, wc = wid & 1;
    const unsigned short* Ab = Wb + (size_t)t * 1048576 + ((size_t)c * M + G0) * K;
    const unsigned short* Tt = T + (size_t)t * 4194304;
    const unsigned short* TbB0 = Tt + ((size_t)bc * WW + W0) * K;
    const unsigned short* TbB1 = Tt + (size_t)bc * K * WW;
    const int arow0 = tx >> 3;
    const int wseg = tx & 15, fgrp = tx >> 4;
    f32x4 acc[2][4];
#pragma unroll
    for (int i = 0; i < 2; ++i)
#pragma unroll
        for (int j = 0; j < 4; ++j) acc[i][j] = (f32x4){0.f, 0.f, 0.f, 0.f};

#define STAGE_A(buf, f0)                                                     \
    _Pragma("unroll")                                                        \
    for (int rep = 0; rep < 2; ++rep) {                                      \
        int row = arow0 + rep * 32;                                          \
        int seg = (tx & 7) ^ (row & 7);                                      \
        gload16(Ab + (size_t)row * K + (f0) + seg * 8,                       \
                (char*)Al[buf] + wid * 1024 + rep * 4096);                   \
    }
#define STAGE_B0(buf, f0)                                                    \
    _Pragma("unroll")                                                        \
    for (int rep = 0; rep < 4; ++rep) {                                      \
        int row = arow0 + rep * 32;                                          \
        int seg = (tx & 7) ^ (row & 7) ^ ((row >> 3) & 7);                   \
        gload16(TbB0 + (size_t)row * K + (f0) + seg * 8,                     \
                (char*)Bl[buf] + wid * 1024 + rep * 4096);                   \
    }
#define GATHER_B1(f0)                                                        \
    _Pragma("unroll")                                                        \
    for (int i = 0; i < 4; ++i)                                              \
        tv[i] = *(const us8*)(TbB1 + (size_t)((f0) + fgrp * 4 + i) * WW + W0 + wseg * 8);
#define WRITE_B1(buf)                                                        \
    _Pragma("unroll")                                                        \
    for (int j = 0; j < 8; ++j) {                                            \
        int w = wseg * 8 + j;                                                \
        us4 p; p.x = tv[0][j]; p.y = tv[1][j]; p.z = tv[2][j]; p.w = tv[3][j]; \
        *(us4*)((char*)Bl[buf] + w * 128 +                                   \
                ((((fgrp >> 1) ^ (w & 7) ^ ((w >> 3) & 7)) << 4)) + (fgrp & 1) * 8) = p; \
    }

    us8 tv[4];
    STAGE_A(0, 0)
    if (BSRC == 0) { STAGE_B0(0, 0) } else { GATHER_B1(0) WRITE_B1(0) }
    __syncthreads();
    int cur = 0;
    for (int k = 0; k < NK; ++k) {
        const int f0n = (k + 1) * 64;
        if (k + 1 < NK) {
            STAGE_A(cur ^ 1, f0n)
            if (BSRC == 0) { STAGE_B0(cur ^ 1, f0n) }
            else { GATHER_B1(f0n) }
        }
#pragma unroll
        for (int kc = 0; kc < 2; ++kc) {
            bf16x8 af[2], bf[4];
#pragma unroll
            for (int i = 0; i < 2; ++i) {
                int gr = wr * 32 + i * 16 + lr;
                af[i] = *(const bf16x8*)((char*)Al[cur] + gr * 128 +
                        (((kc * 4 + lg) ^ (gr & 7)) << 4));
            }
#pragma unroll
            for (int j = 0; j < 4; ++j) {
                int wrw = wc * 64 + j * 16 + lr;
                bf[j] = *(const bf16x8*)((char*)Bl[cur] + wrw * 128 +
                        (((kc * 4 + lg) ^ (wrw & 7) ^ ((wrw >> 3) & 7)) << 4));
            }
#pragma unroll
            for (int i = 0; i < 2; ++i)
#pragma unroll
                for (int j = 0; j < 4; ++j)
                    acc[i][j] = mfma16(af[i], bf[j], acc[i][j]);
        }
        if (BSRC == 1 && k + 1 < NK) { WRITE_B1(cur ^ 1) }
        __syncthreads();
        cur ^= 1;
    }
#undef STAGE_A
#undef STAGE_B0
#undef GATHER_B1
#undef WRITE_B1
#pragma unroll
    for (int i = 0; i < 2; ++i)
#pragma unroll
        for (int j = 0; j < 4; ++j) {
            int g2 = G0 + wr * 32 + i * 16 + lg * 4;
            int w = W0 + wc * 64 + j * 16 + lr;
#pragma unroll
            for (int r = 0; r < 4; ++r) {
                size_t o = (size_t)t * 4194304 + ((size_t)bc * M + g2 + r) * WW + w;
                if (MODE == 0) ob[o] = f2bf(acc[i][j][r]);
                else of[o] += acc[i][j][r];
            }
        }
}

// ---------------- 128x128-tile MFMA GEMM (FFN-up), coalesced MODE2 epilogue ----------------
template <int K, int M, int MODE>
__global__ __launch_bounds__(256, 2) void mgemm2(
    const unsigned short* __restrict__ Wb, const unsigned short* __restrict__ T,
    unsigned short* __restrict__ ob, float* __restrict__ of) {
    __shared__ __align__(16) unsigned short SH[2][128 * 64];
    unsigned short* Al = SH[0];
    unsigned short* Bl = SH[1];
    const int id = blockIdx.x;
    const int grp = ((id >> 6) << 3) | (id & 7);
    const int g = (id >> 3) & 7;
    const int bc = grp >> 2, z = grp & 3;
    const int c = bc & 15;
    const int G0 = g * 128, W0 = z * 128;
    const int tx = threadIdx.x;
    const int lane = tx & 63, wid = tx >> 6;
    const int lr = lane & 15, lg = lane >> 4;
    const int wr = wid >> 1, wc = wid & 1;
    const unsigned short* Ab = Wb + ((size_t)c * M + G0) * K;
    f32x4 acc[4][4];
#pragma unroll
    for (int i = 0; i < 4; ++i)
#pragma unroll
        for (int j = 0; j < 4; ++j) acc[i][j] = (f32x4){0.f, 0.f, 0.f, 0.f};

    const int arow0 = tx >> 3;

    for (int f0 = 0; f0 < K; f0 += 64) {
#pragma unroll
        for (int rep = 0; rep < 4; ++rep) {
            int row = arow0 + rep * 32;
            int seg = (tx & 7) ^ (row & 7);
            gload16(Ab + (size_t)row * K + f0 + seg * 8,
                    (char*)Al + wid * 1024 + rep * 4096);
        }
        {
            const unsigned short* Tb = T + ((size_t)bc * WW + W0) * K;
#pragma unroll
            for (int rep = 0; rep < 4; ++rep) {
                int row = arow0 + rep * 32;
                int seg = (tx & 7) ^ (row & 7) ^ ((row >> 3) & 7);
                gload16(Tb + (size_t)row * K + f0 + seg * 8,
                        (char*)Bl + wid * 1024 + rep * 4096);
            }
        }
        __syncthreads();
#pragma unroll
        for (int kc = 0; kc < 2; ++kc) {
            bf16x8 af[4], bf[4];
#pragma unroll
            for (int i = 0; i < 4; ++i) {
                int gr = wr * 64 + i * 16 + lr;
                af[i] = *(const bf16x8*)((char*)Al + gr * 128 +
                        (((kc * 4 + lg) ^ (gr & 7)) << 4));
                int wrw = wc * 64 + i * 16 + lr;
                bf[i] = *(const bf16x8*)((char*)Bl + wrw * 128 +
                        (((kc * 4 + lg) ^ (wrw & 7) ^ ((wrw >> 3) & 7)) << 4));
            }
#pragma unroll
            for (int i = 0; i < 4; ++i)
#pragma unroll
                for (int j = 0; j < 4; ++j)
                    acc[i][j] = mfma16(af[i], bf[j], acc[i][j]);
        }
        __syncthreads();
    }
    if (MODE == 2) {
        char* S = (char*)SH;
#pragma unroll
        for (int i = 0; i < 4; ++i)
#pragma unroll
            for (int j = 0; j < 4; ++j) {
                int wl = wc * 64 + j * 16 + lr;
                int gl = wr * 64 + i * 16 + lg * 4;
                us4 pk;
                pk.x = f2bf(acc[i][j][0]); pk.y = f2bf(acc[i][j][1]);
                pk.z = f2bf(acc[i][j][2]); pk.w = f2bf(acc[i][j][3]);
                *(us4*)(S + wl * 256 + ((gl * 2) ^ ((wl & 7) << 4))) = pk;
            }
        __syncthreads();
        unsigned short* og = ob + ((size_t)bc * WW + W0) * M + G0;
#pragma unroll
        for (int rep = 0; rep < 8; ++rep) {
            int slot = tx + rep * 256;
            int row = slot >> 4, col = slot & 15;
            us8 v = *(const us8*)(S + row * 256 + ((col * 16) ^ ((row & 7) << 4)));
            *(us8*)(og + (size_t)row * M + col * 8) = v;
        }
    } else {
#pragma unroll
        for (int i = 0; i < 4; ++i)
#pragma unroll
            for (int j = 0; j < 4; ++j) {
                int gg = G0 + wr * 64 + i * 16 + lg * 4;
                int w = W0 + wc * 64 + j * 16 + lr;
#pragma unroll
                for (int r = 0; r < 4; ++r) {
                    size_t o = ((size_t)bc * M + gg + r) * WW + w;
                    if (MODE == 0) ob[o] = f2bf(acc[i][j][r]);
                    else of[o] += acc[i][j][r];
                }
            }
    }
}

// ---------------- fused attention v4: V read direct from global (L2-resident) ----------------
__global__ __launch_bounds__(256, 2) void attn_fused(
    const unsigned short* __restrict__ qb, const unsigned short* __restrict__ kb,
    const unsigned short* __restrict__ vb, float* __restrict__ qko,
    unsigned short* __restrict__ abT) {
    __shared__ unsigned short Kl[512 * 32];
    __shared__ unsigned short Ql[64 * 32];
    const int bch = blockIdx.x, qt = blockIdx.y;
    const int bc = bch >> 3, h = bch & 7;
    const int tx = threadIdx.x;
    const int lane = tx & 63, wid = tx >> 6;
    const int lr = lane & 15, lg = lane >> 4;

    const unsigned short* kbase = kb + ((size_t)bc * FF + h * DH) * WW;
    const unsigned short* vbase = vb + ((size_t)bc * FF + h * DH) * WW;
    const unsigned short* qbase = qb + ((size_t)bc * FF + h * DH) * WW + qt * 64;

    {
        int d0 = ((tx >> 3) & 7) * 4;
#pragma unroll
        for (int rep = 0; rep < 2; ++rep) {
            int kw0 = (tx & 7) * 8 + ((tx >> 6) & 3) * 64 + rep * 256;
            us8 v0 = *(const us8*)(kbase + (size_t)(d0 + 0) * WW + kw0);
            us8 v1 = *(const us8*)(kbase + (size_t)(d0 + 1) * WW + kw0);
            us8 v2 = *(const us8*)(kbase + (size_t)(d0 + 2) * WW + kw0);
            us8 v3 = *(const us8*)(kbase + (size_t)(d0 + 3) * WW + kw0);
#pragma unroll
            for (int j = 0; j < 8; ++j) {
                int kw = kw0 + j;
                us4 p; p.x = v0[j]; p.y = v1[j]; p.z = v2[j]; p.w = v3[j];
                *(us4*)((char*)Kl + kw * 64 + ((d0 * 2) ^ ((kw & 3) << 4))) = p;
            }
        }
    }
    if (tx < 64) {
        int d0 = ((tx >> 3) & 7) * 4;
        int q0 = (tx & 7) * 8;
        us8 v0 = *(const us8*)(qbase + (size_t)(d0 + 0) * WW + q0);
        us8 v1 = *(const us8*)(qbase + (size_t)(d0 + 1) * WW + q0);
        us8 v2 = *(const us8*)(qbase + (size_t)(d0 + 2) * WW + q0);
        us8 v3 = *(const us8*)(qbase + (size_t)(d0 + 3) * WW + q0);
#pragma unroll
        for (int j = 0; j < 8; ++j) {
            us4 p; p.x = v0[j]; p.y = v1[j]; p.z = v2[j]; p.w = v3[j];
            *(us4*)(&Ql[(q0 + j) * 32 + d0]) = p;
        }
    }
    __syncthreads();

    const int q0w = wid * 16;
    bf16x8 qf = *(const bf16x8*)((char*)Ql + (q0w + lr) * 64 + lg * 16);
    f32x4 s[32];
#pragma unroll
    for (int i = 0; i < 32; ++i) s[i] = (f32x4){0.f, 0.f, 0.f, 0.f};
#pragma unroll
    for (int kwt = 0; kwt < 32; ++kwt) {
        int krow = kwt * 16 + lr;
        bf16x8 kf = *(const bf16x8*)((char*)Kl + krow * 64 + ((lg * 16) ^ ((krow & 3) << 4)));
        s[kwt] = mfma16(kf, qf, s[kwt]);
    }
    float mx = -3.0e38f;
    float* qrow = qko + ((size_t)bch * WW + qt * 64 + q0w + lr) * WW;
#pragma unroll
    for (int kwt = 0; kwt < 32; ++kwt) {
        s[kwt] *= 0.0625f;
        float4 st;
        st.x = s[kwt][0]; st.y = s[kwt][1]; st.z = s[kwt][2]; st.w = s[kwt][3];
        *(float4*)(qrow + kwt * 16 + lg * 4) = st;
        mx = fmaxf(mx, fmaxf(fmaxf(st.x, st.y), fmaxf(st.z, st.w)));
    }
    mx = fmaxf(mx, __shfl_xor(mx, 16));
    mx = fmaxf(mx, __shfl_xor(mx, 32));
    float sum = 0.f;
#pragma unroll
    for (int kwt = 0; kwt < 32; ++kwt) {
#pragma unroll
        for (int r = 0; r < 4; ++r) {
            float p = __expf(s[kwt][r] - mx);
            s[kwt][r] = p;
            sum += p;
        }
    }
    sum += __shfl_xor(sum, 16);
    sum += __shfl_xor(sum, 32);
    float inv = 1.0f / sum;

    f32x4 av[2];
    av[0] = (f32x4){0.f, 0.f, 0.f, 0.f};
    av[1] = (f32x4){0.f, 0.f, 0.f, 0.f};
#pragma unroll
    for (int t = 0; t < 16; ++t) {
        unsigned pa0 = f2bf(s[2 * t][0]) | ((unsigned)f2bf(s[2 * t][1]) << 16);
        unsigned pa1 = f2bf(s[2 * t][2]) | ((unsigned)f2bf(s[2 * t][3]) << 16);
        unsigned pb0 = f2bf(s[2 * t + 1][0]) | ((unsigned)f2bf(s[2 * t + 1][1]) << 16);
        unsigned pb1 = f2bf(s[2 * t + 1][2]) | ((unsigned)f2bf(s[2 * t + 1][3]) << 16);
        unsigned s16_0 = (lg == 1) ? pa0 : pb0, s16_1 = (lg == 1) ? pa1 : pb1;
        unsigned s32_0 = (lg == 3) ? pa0 : pb0, s32_1 = (lg == 3) ? pa1 : pb1;
        unsigned s48_0 = (lg == 2) ? pa0 : pb0, s48_1 = (lg == 2) ? pa1 : pb1;
        unsigned r16_0 = (unsigned)__shfl_xor((int)s16_0, 16);
        unsigned r16_1 = (unsigned)__shfl_xor((int)s16_1, 16);
        unsigned r32_0 = (unsigned)__shfl_xor((int)s32_0, 32);
        unsigned r32_1 = (unsigned)__shfl_xor((int)s32_1, 32);
        unsigned r48_0 = (unsigned)__shfl_xor((int)s48_0, 48);
        unsigned r48_1 = (unsigned)__shfl_xor((int)s48_1, 48);
        uint4 wv;
        if (lg == 0)      { wv.x = pa0;   wv.y = pa1;   wv.z = r16_0; wv.w = r16_1; }
        else if (lg == 1) { wv.x = r48_0; wv.y = r48_1; wv.z = r32_0; wv.w = r32_1; }
        else if (lg == 2) { wv.x = r32_0; wv.y = r32_1; wv.z = r48_0; wv.w = r48_1; }
        else              { wv.x = r16_0; wv.y = r16_1; wv.z = pb0;  wv.w = pb1; }
        bf16x8 pf = *reinterpret_cast<bf16x8*>(&wv);
#pragma unroll
        for (int di = 0; di < 2; ++di) {
            int vr = di * 16 + lr;
            bf16x8 vf = *(const bf16x8*)(vbase + (size_t)vr * WW + t * 32 + lg * 8);
            av[di] = mfma16(vf, pf, av[di]);
        }
    }
    unsigned short* arow = abT + ((size_t)bc * WW + qt * 64 + q0w + lr) * FF + h * DH;
#pragma unroll
    for (int di = 0; di < 2; ++di) {
        us4 pk;
        pk.x = f2bf(av[di][0] * inv); pk.y = f2bf(av[di][1] * inv);
        pk.z = f2bf(av[di][2] * inv); pk.w = f2bf(av[di][3] * inv);
        *(us4*)(arow + di * 16 + lg * 4) = pk;
    }
}

// ---------------- LDS-tiled depthwise 16-ch mix ----------------
template <int NPC, int MODE, int TILE>
__global__ __launch_bounds__(256) void dwmix(
    const unsigned short* __restrict__ in, const float* __restrict__ wdw,
    const float* __restrict__ x, float* __restrict__ fo, unsigned short* __restrict__ bo) {
    __shared__ unsigned short L[16][TILE];
    constexpr int C8 = TILE / 8;
    constexpr int LV = TILE / 128;
    constexpr int PER = TILE / 256;
    int b = blockIdx.y;
    size_t base = (size_t)blockIdx.x * TILE;
    int tx = threadIdx.x;
#pragma unroll
    for (int r = 0; r < LV; ++r) {
        int idx = tx + r * 256;
        int ci = idx / C8;
        int seg = idx % C8;
        *(us8*)&L[ci][seg * 8] = *(const us8*)(in + ((size_t)(b * 16 + ci)) * NPC + base + seg * 8);
    }
    __syncthreads();
#pragma unroll
    for (int pos = 0; pos < PER; ++pos) {
        int fw = tx + pos * 256;
        float vin[16];
#pragma unroll
        for (int ci = 0; ci < 16; ++ci) vin[ci] = bf2f(L[ci][fw]);
#pragma unroll
        for (int o = 0; o < 16; ++o) {
            float s = 0.f;
#pragma unroll
            for (int ci = 0; ci < 16; ++ci) s += wdw[o * 16 + ci] * vin[ci];
            size_t oi = ((size_t)(b * 16 + o)) * NPC + base + fw;
            if (MODE == 0) fo[oi] = x[oi] + s;
            else { s = fmaxf(s, 0.f); bo[oi] = f2bf(s * s); }
        }
    }
}

extern "C" void kernel_launch(void* const* d_in, const int* in_sizes, int n_in,
                              void* d_out, int out_size, void* d_ws, size_t ws_size,
                              hipStream_t stream) {
    const float* x      = (const float*)d_in[0];
    const float* conv_q = (const float*)d_in[1];
    const float* conv_k = (const float*)d_in[2];
    const float* conv_v = (const float*)d_in[3];
    const float* wq     = (const float*)d_in[4];
    const float* wk     = (const float*)d_in[5];
    const float* wv     = (const float*)d_in[6];
    const float* wo_pw  = (const float*)d_in[7];
    const float* wo_dw  = (const float*)d_in[8];
    const float* g1     = (const float*)d_in[9];
    const float* b1     = (const float*)d_in[10];
    const float* g2     = (const float*)d_in[11];
    const float* b2     = (const float*)d_in[12];
    const float* w1_pw  = (const float*)d_in[13];
    const float* w1_dw  = (const float*)d_in[14];
    const float* w2_pw  = (const float*)d_in[15];

    float* hout  = (float*)d_out;
    float* qkout = (float*)d_out + 4194304;

    char* ws = (char*)d_ws;
    const size_t MB1 = (size_t)1 << 20;
    unsigned short* n1   = (unsigned short*)(ws + 0 * MB1);
    unsigned short* cq   = (unsigned short*)(ws + 8 * MB1);    // cq/ck/cv contiguous
    unsigned short* qb   = (unsigned short*)(ws + 32 * MB1);   // qb/kb/vb contiguous
    unsigned short* kb   = (unsigned short*)(ws + 40 * MB1);
    unsigned short* vb   = (unsigned short*)(ws + 48 * MB1);
    unsigned short* abT  = (unsigned short*)(ws + 56 * MB1);
    unsigned short* pwb  = (unsigned short*)(ws + 64 * MB1);
    unsigned short* n2t  = (unsigned short*)(ws + 72 * MB1);
    unsigned short* u1t  = (unsigned short*)(ws + 80 * MB1);   // 32 MB
    unsigned short* u2t  = (unsigned short*)(ws + 112 * MB1);  // 32 MB
    unsigned short* Wqkv = (unsigned short*)(ws + 144 * MB1);  // 6 MB
    unsigned short* Wo16 = (unsigned short*)(ws + 150 * MB1);  // 2 MB
    unsigned short* W116 = (unsigned short*)(ws + 152 * MB1);  // 8 MB
    unsigned short* W216 = (unsigned short*)(ws + 160 * MB1);  // 8 MB
    unsigned short* Awb  = (unsigned short*)(ws + 168 * MB1);  // 15 KB

    prep_ln<<<dim3(6686), 256, 0, stream>>>(x, g1, b1, n1,
                                            wq, wk, wv, wo_pw, w1_pw, w2_pw,
                                            conv_q, conv_k, conv_v,
                                            Wqkv, Wo16, W116, W216, Awb);
    conv3_mfma<<<dim3(8, 64, BB), 256, 0, stream>>>(n1, Awb, cq, cq + 4194304, cq + 8388608);
    mgemm3<256, 1, 0, 3><<<dim3(1536), 256, 0, stream>>>(Wqkv, cq, qb, nullptr);
    attn_fused<<<dim3(BC * HH, 8), 256, 0, stream>>>(qb, kb, vb, qkout, abT);
    mgemm3<256, 0, 0, 1><<<dim3(512), 256, 0, stream>>>(Wo16, abT, pwb, nullptr);
    dwmix<131072, 0, 256><<<dim3(512, BB), 256, 0, stream>>>(pwb, wo_dw, x, hout, nullptr);
    ln2t_kernel<<<dim3(BC, 16), 256, 0, stream>>>(hout, g2, b2, n2t);
    mgemm2<256, 1024, 2><<<dim3(1024), 256, 0, stream>>>(W116, n2t, u1t, nullptr);
    dwmix<524288, 1, 1024><<<dim3(512, BB), 256, 0, stream>>>(u1t, w1_dw, nullptr, nullptr, u2t);
    mgemm3<1024, 0, 1, 1><<<dim3(512), 256, 0, stream>>>(W216, u2t, nullptr, hout);
}